// Round 4
// baseline (580.144 us; speedup 1.0000x reference)
//
#include <hip/hip_runtime.h>
#include <hip/hip_bf16.h>

typedef unsigned int u32;
typedef unsigned short u16;
typedef unsigned long long u64;

using bf16x8 = __attribute__((ext_vector_type(8))) short;
using f32x4  = __attribute__((ext_vector_type(4))) float;

#define NUNITS 31
#define WS_BIAS_OFF (NUNITS*8192)
#define NBIAS 1952

__device__ __forceinline__ u32 pk2(float a, float b){
    __hip_bfloat162 h = __float22bfloat162_rn(make_float2(a, b));
    union { __hip_bfloat162 h2; u32 u; } cv; cv.h2 = h; return cv.u;
}
__device__ __forceinline__ float b2f(u16 v){ return __uint_as_float(((u32)v) << 16); }
__device__ __forceinline__ int swch(int chunk, int key){ return (chunk & ~7) | ((chunk ^ key) & 7); }

// ---------------- weight pre-conversion (identical layout to R3) ----------------
__global__ __launch_bounds__(256) void convert_weights(
    const float* __restrict__ enc_w,
    const float* __restrict__ q1, const float* __restrict__ k1,
    const float* __restrict__ v1, const float* __restrict__ o1,
    const float* __restrict__ q2, const float* __restrict__ k2,
    const float* __restrict__ v2, const float* __restrict__ o2,
    const float* __restrict__ gih, const float* __restrict__ ghh,
    const float* __restrict__ lin,
    const float* __restrict__ enc_b,
    const float* __restrict__ q1b, const float* __restrict__ k1b,
    const float* __restrict__ v1b, const float* __restrict__ o1b,
    const float* __restrict__ q2b, const float* __restrict__ k2b,
    const float* __restrict__ v2b, const float* __restrict__ o2b,
    const float* __restrict__ gbih, const float* __restrict__ gbhh,
    const float* __restrict__ linb,
    u16* __restrict__ dst)
{
    int idx = blockIdx.x*256 + threadIdx.x;
    if (idx < NUNITS*8192){
        int u = idx >> 13, rem = idx & 8191;
        int row = rem >> 6, ci = rem & 63;
        int p = ci >> 3, e = ci & 7;
        int lc = (((p ^ (row & 7)) & 7) << 3) | e;
        float val;
        if (u == 0){
            val = enc_w[row*64 + lc];
        } else if (u <= 16){
            int v = u - 1; int kh = v & 1;
            const float* s;
            switch (v >> 1){ case 0: s=q1; break; case 1: s=k1; break; case 2: s=v1; break;
                             case 3: s=o1; break; case 4: s=q2; break; case 5: s=k2; break;
                             case 6: s=v2; break; default: s=o2; }
            val = s[row*128 + kh*64 + lc];
        } else if (u <= 28){
            int v = u - 17; int kh = v & 1; int gate = v >> 2;
            const float* s = ((v >> 1) & 1) ? ghh : gih;
            val = s[(gate*128 + row)*128 + kh*64 + lc];
        } else {
            int kh = u - 29;
            val = (row < 20) ? lin[row*128 + kh*64 + lc] : 0.f;
        }
        __hip_bfloat16 hv = __float2bfloat16(val);
        union { __hip_bfloat16 h; u16 us; } cv; cv.h = hv;
        dst[idx] = cv.us;
    } else if (idx < NUNITS*8192 + NBIAS){
        int i = idx - NUNITS*8192;
        float val;
        if      (i < 128)  val = enc_b[i];
        else if (i < 256)  val = q1b[i-128];
        else if (i < 384)  val = k1b[i-256];
        else if (i < 512)  val = v1b[i-384];
        else if (i < 640)  val = o1b[i-512];
        else if (i < 768)  val = q2b[i-640];
        else if (i < 896)  val = k2b[i-768];
        else if (i < 1024) val = v2b[i-896];
        else if (i < 1152) val = o2b[i-1024];
        else if (i < 1536) val = gbih[i-1152];
        else if (i < 1920) val = gbhh[i-1536];
        else if (i < 1940) val = linb[i-1920];
        else               val = 0.f;
        ((float*)(dst + NUNITS*8192))[i] = val;
    }
}

// ---------------- pipeline primitives ----------------
#define BARX() do{ asm volatile("s_waitcnt lgkmcnt(0)" ::: "memory"); \
                   __builtin_amdgcn_s_barrier(); \
                   asm volatile("" ::: "memory"); }while(0)
#define WAITV(N) asm volatile("s_waitcnt vmcnt(" #N ")" ::: "memory")

__device__ __forceinline__ void issue_unit(const u16* Wu, u16* WBs, int u, int tid){
    u16* slot = WBs + (u & 1) * 8192;
    const u16* src = Wu + u * 8192;
    #pragma unroll
    for (int t = 0; t < 4; t++){
        __builtin_amdgcn_global_load_lds(
            (const __attribute__((address_space(1))) void*)(src + t*2048 + tid*8),
            (__attribute__((address_space(3))) void*)(slot + t*2048 + tid*8),
            16, 0, 0);
    }
}
#define SLOT(U) (WBs + ((U) & 1) * 8192)
#define PRE(UNEXT) do{ BARX(); issue_unit(Wu, WBs, (UNEXT), tid); WAITV(4); BARX(); }while(0)

template<int M,int N>
__device__ __forceinline__ void zacc(f32x4 (&a)[M][N]){
    #pragma unroll
    for (int i=0;i<M;i++)
        #pragma unroll
        for (int j=0;j<N;j++) a[i][j] = (f32x4){0.f,0.f,0.f,0.f};
}

// Y = X @ W^T (one 64-k half). Wave w owns oc-tiles {2w,2w+1}, all 4 token-tiles.
template<int KH>
__device__ __forceinline__ void wgemm(const u16* Wb, const u16* X,
                                      int w, int c, int g, f32x4 (&acc)[2][4]){
    const int key = c & 7;
    #pragma unroll
    for (int kk = 0; kk < 2; kk++){
        const int pw = (kk*4 + g) ^ key;
        bf16x8 a[2];
        #pragma unroll
        for (int i = 0; i < 2; i++)
            a[i] = *(const bf16x8*)(Wb + ((w*2+i)*16 + c)*64 + pw*8);
        #pragma unroll
        for (int j = 0; j < 4; j++){
            bf16x8 b = *(const bf16x8*)(X + (j*16 + c)*128 + (KH*8 + pw)*8);
            #pragma unroll
            for (int i = 0; i < 2; i++)
                acc[i][j] = __builtin_amdgcn_mfma_f32_16x16x32_bf16(a[i], b, acc[i][j], 0,0,0);
        }
    }
}

// V-GEMM: out[token][vcol]; wave w owns vcol-tiles {2w,2w+1}, all 4 token-tiles.
template<int KH>
__device__ __forceinline__ void vgemm(const u16* Wb, const u16* X,
                                      int w, int c, int g, f32x4 (&acc)[4][2]){
    const int key = c & 7;
    #pragma unroll
    for (int kk = 0; kk < 2; kk++){
        const int pw = (kk*4 + g) ^ key;
        bf16x8 a[4];
        #pragma unroll
        for (int i = 0; i < 4; i++)
            a[i] = *(const bf16x8*)(X + ((i*16 + c)*128) + (KH*8 + pw)*8);
        #pragma unroll
        for (int j = 0; j < 2; j++){
            bf16x8 b = *(const bf16x8*)(Wb + ((w*2+j)*16 + c)*64 + pw*8);
            #pragma unroll
            for (int i = 0; i < 4; i++)
                acc[i][j] = __builtin_amdgcn_mfma_f32_16x16x32_bf16(a[i], b, acc[i][j], 0,0,0);
        }
    }
}

__device__ __forceinline__ void epiW(f32x4 (&acc)[2][4], float4 bv0, float4 bv1,
                                     u16* dst, int w, int c, int g){
    const int key = c & 7;
    #pragma unroll
    for (int i = 0; i < 2; i++){
        float4 bv = i ? bv1 : bv0;
        const int col0 = (w*2+i)*16 + g*4;
        const int coff = swch(col0>>3, key)*8 + (col0&7);
        #pragma unroll
        for (int j = 0; j < 4; j++){
            int row = j*16 + c;
            float v0 = fmaxf(acc[i][j][0]+bv.x, 0.f);
            float v1 = fmaxf(acc[i][j][1]+bv.y, 0.f);
            float v2 = fmaxf(acc[i][j][2]+bv.z, 0.f);
            float v3 = fmaxf(acc[i][j][3]+bv.w, 0.f);
            uint2 o; o.x = pk2(v0,v1); o.y = pk2(v2,v3);
            *(uint2*)(dst + row*128 + coff) = o;
        }
    }
}

// ---------------- main fused kernel: 1 batch item / block, 256 threads ----------------
__global__ __launch_bounds__(256, 2) void drgn_pipe(
    const float* __restrict__ x, const int* __restrict__ maskg,
    const float* __restrict__ h0, const u16* __restrict__ W16,
    float* __restrict__ out_qs, float* __restrict__ out_h3)
{
    __shared__ __align__(16) u16 SMEM[40960];   // exactly 81920 B
    u16* ACT = SMEM;                 // [64][128] acts / [128][64] V^T / h3
    u16* QXp = SMEM + 8192;          // x-in / Q / X1 / h0-bf16
    u16* KPp = SMEM + 16384;         // K  (transient: mask u64[64] at start)
    u16* WBs = SMEM + 24576;         // 2 x 16KB weight ring

    const int tid = threadIdx.x;
    const int w = tid >> 6, lane = tid & 63;
    const int c = lane & 15, g = lane >> 4;
    const int key = c & 7;
    const size_t rowbase = (size_t)blockIdx.x * 64;
    const u16* Wu = W16;
    const float* wsb = (const float*)(W16 + WS_BIAS_OFF);
    const int col00 = (w*2)*16 + g*4;
    const int col01 = col00 + 16;

    // ---- prologue: mask bits -> regs (via KP transient), x -> QX bf16 ----
    u64* MrowT = (u64*)KPp;
    #pragma unroll 4
    for (int rr = 0; rr < 16; rr++){
        int row = w*16 + rr;
        int mv = maskg[(rowbase + row)*64 + lane];
        u64 bits = __ballot(mv != 0);
        if (lane == 0) MrowT[row] = bits;
    }
    for (int i = tid; i < 512; i += 256){
        int row = i >> 3, p = i & 7;
        int lc = (p ^ (row & 7)) & 7;
        const float* sp = x + (rowbase + row)*64 + lc*8;
        float4 f0 = *(const float4*)sp;
        float4 f1 = *(const float4*)(sp + 4);
        uint4 o; o.x = pk2(f0.x,f0.y); o.y = pk2(f0.z,f0.w);
        o.z = pk2(f1.x,f1.y); o.w = pk2(f1.z,f1.w);
        *(uint4*)(QXp + row*128 + p*8) = o;
    }
    __syncthreads();
    u64 mbits[4];
    #pragma unroll
    for (int qt = 0; qt < 4; qt++) mbits[qt] = MrowT[qt*16 + c];

    issue_unit(Wu, WBs, 0, tid);

    f32x4 acc[2][4];

    // ---- encoder (unit 0): ACT = relu(x @ enc^T + b) ----
    {
        BARX();
        float4 b0 = *(const float4*)(wsb + col00);
        float4 b1 = *(const float4*)(wsb + col01);
        issue_unit(Wu, WBs, 1, tid);
        WAITV(4); BARX();
        zacc(acc);
        wgemm<0>(SLOT(0), QXp, w, c, g, acc);
        epiW(acc, b0, b1, ACT, w, c, g);
    }

    // ---- two MHA layers ----
    #pragma unroll 1
    for (int layer = 0; layer < 2; layer++){
        const int ub = 1 + layer*8;
        const int bb = 128 + layer*512;

        // Q (units ub, ub+1) -> QXp
        BARX();
        float4 bq0 = *(const float4*)(wsb + bb + col00);
        float4 bq1 = *(const float4*)(wsb + bb + col01);
        issue_unit(Wu, WBs, ub+1, tid);
        WAITV(4); BARX();
        zacc(acc); wgemm<0>(SLOT(ub), ACT, w, c, g, acc);
        PRE(ub+2);
        wgemm<1>(SLOT(ub+1), ACT, w, c, g, acc);
        epiW(acc, bq0, bq1, QXp, w, c, g);

        // K (units ub+2, ub+3) -> KPp
        BARX();
        float4 bk0 = *(const float4*)(wsb + bb + 128 + col00);
        float4 bk1 = *(const float4*)(wsb + bb + 128 + col01);
        issue_unit(Wu, WBs, ub+3, tid);
        WAITV(4); BARX();
        zacc(acc); wgemm<0>(SLOT(ub+2), ACT, w, c, g, acc);
        PRE(ub+4);
        wgemm<1>(SLOT(ub+3), ACT, w, c, g, acc);
        epiW(acc, bk0, bk1, KPp, w, c, g);

        // V (units ub+4, ub+5) -> registers
        f32x4 vacc[4][2];
        BARX();
        float bv0 = wsb[bb + 256 + w*32 + c];
        float bv1 = wsb[bb + 256 + w*32 + 16 + c];
        issue_unit(Wu, WBs, ub+5, tid);
        WAITV(4); BARX();
        zacc(vacc); vgemm<0>(SLOT(ub+4), ACT, w, c, g, vacc);
        PRE(ub+6);
        vgemm<1>(SLOT(ub+5), ACT, w, c, g, vacc);

        BARX();   // all ACT reads done -> overwrite with V^T [128 vcol][64 tok]
        #pragma unroll
        for (int j = 0; j < 2; j++){
            int vrow = w*32 + j*16 + c;
            float bv = j ? bv1 : bv0;
            #pragma unroll
            for (int i = 0; i < 4; i++){
                int kk = i >> 1, p = i & 1;
                float v0 = fmaxf(vacc[i][j][0]+bv, 0.f);
                float v1 = fmaxf(vacc[i][j][1]+bv, 0.f);
                float v2 = fmaxf(vacc[i][j][2]+bv, 0.f);
                float v3 = fmaxf(vacc[i][j][3]+bv, 0.f);
                uint2 o; o.x = pk2(v0,v1); o.y = pk2(v2,v3);
                *(uint2*)(ACT + vrow*64 + swch(kk*4+g, key)*8 + p*4) = o;
            }
        }

        // scores: mfma(K, Q) -> lane c = q-row, (g,r) = k-token
        const int h = w;
        f32x4 sc[4][4];
        {
            bf16x8 kf[4];
            #pragma unroll
            for (int kt = 0; kt < 4; kt++)
                kf[kt] = *(const bf16x8*)(KPp + (kt*16 + c)*128 + swch(h*4+g, key)*8);
            #pragma unroll
            for (int qt = 0; qt < 4; qt++){
                bf16x8 qf = *(const bf16x8*)(QXp + (qt*16 + c)*128 + swch(h*4+g, key)*8);
                #pragma unroll
                for (int kt = 0; kt < 4; kt++){
                    f32x4 z4 = (f32x4){0.f,0.f,0.f,0.f};
                    sc[qt][kt] = __builtin_amdgcn_mfma_f32_16x16x32_bf16(kf[kt], qf, z4, 0,0,0);
                }
            }
        }
        BARX();   // Q/K reads + V^T writes complete

        {   // in-register masked softmax + PV
            u32 pp[4][4][2];
            #pragma unroll
            for (int qt = 0; qt < 4; qt++){
                u64 mb = mbits[qt];
                float mx = -1e30f;
                #pragma unroll
                for (int kt = 0; kt < 4; kt++)
                    #pragma unroll
                    for (int r = 0; r < 4; r++){
                        float s = sc[qt][kt][r] * 0.17677669529663687f;
                        s = ((mb >> (kt*16 + g*4 + r)) & 1ull) ? s : -1e30f;
                        sc[qt][kt][r] = s;
                        mx = fmaxf(mx, s);
                    }
                mx = fmaxf(mx, __shfl_xor(mx, 16));
                mx = fmaxf(mx, __shfl_xor(mx, 32));
                float sum = 0.f;
                #pragma unroll
                for (int kt = 0; kt < 4; kt++)
                    #pragma unroll
                    for (int r = 0; r < 4; r++){
                        float e = __expf(sc[qt][kt][r] - mx);
                        sc[qt][kt][r] = e; sum += e;
                    }
                sum += __shfl_xor(sum, 16);
                sum += __shfl_xor(sum, 32);
                float inv = 1.f / sum;
                #pragma unroll
                for (int kt = 0; kt < 4; kt++){
                    pp[qt][kt][0] = pk2(sc[qt][kt][0]*inv, sc[qt][kt][1]*inv);
                    pp[qt][kt][1] = pk2(sc[qt][kt][2]*inv, sc[qt][kt][3]*inv);
                }
            }
            #pragma unroll
            for (int dt = 0; dt < 2; dt++){
                f32x4 pa[4];
                #pragma unroll
                for (int qt = 0; qt < 4; qt++) pa[qt] = (f32x4){0.f,0.f,0.f,0.f};
                #pragma unroll
                for (int kk = 0; kk < 2; kk++){
                    bf16x8 vt = *(const bf16x8*)(ACT + (h*32 + dt*16 + c)*64 + ((kk*4+g)^key)*8);
                    #pragma unroll
                    for (int qt = 0; qt < 4; qt++){
                        union { u32 u4[4]; bf16x8 v8; } bbv;
                        bbv.u4[0]=pp[qt][kk*2][0];   bbv.u4[1]=pp[qt][kk*2][1];
                        bbv.u4[2]=pp[qt][kk*2+1][0]; bbv.u4[3]=pp[qt][kk*2+1][1];
                        pa[qt] = __builtin_amdgcn_mfma_f32_16x16x32_bf16(vt, bbv.v8, pa[qt], 0,0,0);
                    }
                }
                #pragma unroll
                for (int qt = 0; qt < 4; qt++){
                    int col = h*32 + dt*16 + g*4;
                    uint2 o; o.x = pk2(pa[qt][0], pa[qt][1]); o.y = pk2(pa[qt][2], pa[qt][3]);
                    *(uint2*)(QXp + (qt*16 + c)*128 + swch(col>>3, key)*8 + (col&7)) = o;
                }
            }
        }

        // O-projection (units ub+6, ub+7): ACT = relu(X1 @ Wo^T + b)
        BARX();
        float4 bo0 = *(const float4*)(wsb + bb + 384 + col00);
        float4 bo1 = *(const float4*)(wsb + bb + 384 + col01);
        issue_unit(Wu, WBs, ub+7, tid);
        WAITV(4); BARX();
        zacc(acc); wgemm<0>(SLOT(ub+6), QXp, w, c, g, acc);

        if (layer == 0){
            PRE(ub+8);
            wgemm<1>(SLOT(ub+7), QXp, w, c, g, acc);
            epiW(acc, bo0, bo1, ACT, w, c, g);
        } else {
            // call 16: prefetch h0 -> regs (T14 split), counted WAITV(12) = 8 h0 + 4 ring
            BARX();
            const float* hp = h0 + (rowbase + (tid>>2))*128 + (tid&3)*32;
            float4 hr[8];
            #pragma unroll
            for (int t = 0; t < 8; t++) hr[t] = *(const float4*)(hp + t*4);
            issue_unit(Wu, WBs, 17, tid);
            WAITV(12); BARX();
            wgemm<1>(SLOT(16), QXp, w, c, g, acc);
            epiW(acc, bo0, bo1, ACT, w, c, g);

            // ---- GRU ----
            f32x4 aI[2][4], aH[2][4];
            float rrA[2][4][4], zzA[2][4][4];
            #pragma unroll 1
            for (int gate = 0; gate < 3; gate++){
                const int u0 = 17 + gate*4;
                // aI = ACT @ Wih^T   (units u0, u0+1)
                BARX();
                if (gate == 0){
                    // h0 regs -> QXp bf16 (QX dead after o-proj reads)
                    int hrow = tid >> 2, seg = tid & 3;
                    #pragma unroll
                    for (int cc = 0; cc < 4; cc++){
                        int p = seg*4 + cc;
                        int ps = (p & 8) | ((p ^ (hrow & 7)) & 7);
                        float4 fa = hr[cc*2], fb = hr[cc*2+1];
                        uint4 o; o.x = pk2(fa.x,fa.y); o.y = pk2(fa.z,fa.w);
                        o.z = pk2(fb.x,fb.y); o.w = pk2(fb.z,fb.w);
                        *(uint4*)(QXp + hrow*128 + ps*8) = o;
                    }
                }
                issue_unit(Wu, WBs, u0+1, tid);
                WAITV(4); BARX();
                zacc(aI); wgemm<0>(SLOT(u0), ACT, w, c, g, aI);
                PRE(u0+2);
                wgemm<1>(SLOT(u0+1), ACT, w, c, g, aI);
                // aH = h0 @ Whh^T   (units u0+2, u0+3)
                BARX();
                float4 bi0 = *(const float4*)(wsb + 1152 + gate*128 + col00);
                float4 bi1 = *(const float4*)(wsb + 1152 + gate*128 + col01);
                float4 bh0 = *(const float4*)(wsb + 1536 + gate*128 + col00);
                float4 bh1 = *(const float4*)(wsb + 1536 + gate*128 + col01);
                issue_unit(Wu, WBs, u0+3, tid);
                WAITV(4); BARX();
                zacc(aH); wgemm<0>(SLOT(u0+2), QXp, w, c, g, aH);
                PRE(u0+4);
                wgemm<1>(SLOT(u0+3), QXp, w, c, g, aH);

                if (gate < 2){
                    #pragma unroll
                    for (int i = 0; i < 2; i++){
                        float4 bi = i ? bi1 : bi0;
                        float4 bh = i ? bh1 : bh0;
                        #pragma unroll
                        for (int j = 0; j < 4; j++)
                            #pragma unroll
                            for (int r = 0; r < 4; r++){
                                float v = aI[i][j][r] + (&bi.x)[r] + aH[i][j][r] + (&bh.x)[r];
                                float s = 1.f/(1.f + __expf(-v));
                                if (gate == 0) rrA[i][j][r] = s; else zzA[i][j][r] = s;
                            }
                    }
                } else {
                    #pragma unroll
                    for (int i = 0; i < 2; i++){
                        float4 bi = i ? bi1 : bi0;
                        float4 bh = i ? bh1 : bh0;
                        int col0 = (w*2+i)*16 + g*4;
                        int coff = swch(col0>>3, key)*8 + (col0&7);
                        #pragma unroll
                        for (int j = 0; j < 4; j++){
                            int row = j*16 + c;
                            uint2 hv = *(const uint2*)(QXp + row*128 + coff);
                            float h0v[4] = { b2f((u16)(hv.x & 0xffffu)), b2f((u16)(hv.x >> 16)),
                                             b2f((u16)(hv.y & 0xffffu)), b2f((u16)(hv.y >> 16)) };
                            float h3v[4];
                            #pragma unroll
                            for (int r = 0; r < 4; r++){
                                float xn = aI[i][j][r] + (&bi.x)[r] + rrA[i][j][r]*(aH[i][j][r] + (&bh.x)[r]);
                                float e2 = __expf(-2.f*fabsf(xn));
                                float th = (1.f - e2)/(1.f + e2);
                                th = (xn >= 0.f) ? th : -th;
                                float zv = zzA[i][j][r];
                                h3v[r] = (1.f - zv)*th + zv*h0v[r];
                            }
                            uint2 o; o.x = pk2(h3v[0],h3v[1]); o.y = pk2(h3v[2],h3v[3]);
                            *(uint2*)(ACT + row*128 + coff) = o;   // h3 -> ACT
                        }
                    }
                }
            }

            // ---- final linear (units 29,30) + stores ----
            f32x4 qa[2][4];
            BARX();
            float4 lb0 = (col00 < 20) ? *(const float4*)(wsb + 1920 + col00)
                                      : (float4){0.f,0.f,0.f,0.f};
            float4 lb1 = (col01 < 20) ? *(const float4*)(wsb + 1920 + col01)
                                      : (float4){0.f,0.f,0.f,0.f};
            issue_unit(Wu, WBs, 30, tid);
            WAITV(4); BARX();
            zacc(qa); wgemm<0>(SLOT(29), ACT, w, c, g, qa);
            BARX();
            WAITV(0); BARX();
            wgemm<1>(SLOT(30), ACT, w, c, g, qa);

            #pragma unroll
            for (int i = 0; i < 2; i++){
                int col0 = (w*2+i)*16 + g*4;
                if (col0 < 20){
                    float4 lb = i ? lb1 : lb0;
                    #pragma unroll
                    for (int j = 0; j < 4; j++){
                        int row = j*16 + c;
                        float4 o;
                        o.x = qa[i][j][0]+lb.x; o.y = qa[i][j][1]+lb.y;
                        o.z = qa[i][j][2]+lb.z; o.w = qa[i][j][3]+lb.w;
                        *(float4*)(out_qs + (rowbase + row)*20 + col0) = o;
                    }
                }
            }
            for (int i2 = tid; i2 < 1024; i2 += 256){
                int row = i2 >> 4, p = i2 & 15;
                int lc2 = (p & 8) | ((p ^ (row & 7)) & 7);
                bf16x8 v = *(const bf16x8*)(ACT + row*128 + p*8);
                float* dp = out_h3 + (rowbase + row)*128 + lc2*8;
                float4 o0, o1;
                o0.x = b2f((u16)v[0]); o0.y = b2f((u16)v[1]); o0.z = b2f((u16)v[2]); o0.w = b2f((u16)v[3]);
                o1.x = b2f((u16)v[4]); o1.y = b2f((u16)v[5]); o1.z = b2f((u16)v[6]); o1.w = b2f((u16)v[7]);
                *(float4*)dp = o0; *(float4*)(dp + 4) = o1;
            }
        }
    }
}

extern "C" void kernel_launch(void* const* d_in, const int* in_sizes, int n_in,
                              void* d_out, int out_size, void* d_ws, size_t ws_size,
                              hipStream_t stream) {
    const float* x     = (const float*)d_in[0];
    const int*   mask  = (const int*)  d_in[1];
    const float* h0    = (const float*)d_in[2];
    const float* enc_w = (const float*)d_in[3];
    const float* enc_b = (const float*)d_in[4];
    const float* q1_w  = (const float*)d_in[5];  const float* q1_b = (const float*)d_in[6];
    const float* k1_w  = (const float*)d_in[7];  const float* k1_b = (const float*)d_in[8];
    const float* v1_w  = (const float*)d_in[9];  const float* v1_b = (const float*)d_in[10];
    const float* o1_w  = (const float*)d_in[11]; const float* o1_b = (const float*)d_in[12];
    const float* q2_w  = (const float*)d_in[13]; const float* q2_b = (const float*)d_in[14];
    const float* k2_w  = (const float*)d_in[15]; const float* k2_b = (const float*)d_in[16];
    const float* v2_w  = (const float*)d_in[17]; const float* v2_b = (const float*)d_in[18];
    const float* o2_w  = (const float*)d_in[19]; const float* o2_b = (const float*)d_in[20];
    const float* gwih  = (const float*)d_in[21]; const float* gwhh = (const float*)d_in[22];
    const float* gbih  = (const float*)d_in[23]; const float* gbhh = (const float*)d_in[24];
    const float* lin_w = (const float*)d_in[25]; const float* lin_b = (const float*)d_in[26];

    const int bs = in_sizes[0] / (64 * 64);           // 4096
    float* out_qs = (float*)d_out;
    float* out_h3 = out_qs + (size_t)bs * 64 * 20;
    u16* W16 = (u16*)d_ws;

    const int total = NUNITS*8192 + NBIAS;
    hipLaunchKernelGGL(convert_weights, dim3((total + 255) / 256), dim3(256), 0, stream,
                       enc_w, q1_w, k1_w, v1_w, o1_w, q2_w, k2_w, v2_w, o2_w,
                       gwih, gwhh, lin_w,
                       enc_b, q1_b, k1_b, v1_b, o1_b, q2_b, k2_b, v2_b, o2_b,
                       gbih, gbhh, lin_b, W16);
    hipLaunchKernelGGL(drgn_pipe, dim3(bs), dim3(256), 0, stream,
                       x, mask, h0, W16, out_qs, out_h3);
}

// Round 5
// 387.831 us; speedup vs baseline: 1.4959x; 1.4959x over previous
//
#include <hip/hip_runtime.h>
#include <hip/hip_bf16.h>

typedef unsigned int u32;
typedef unsigned short u16;
typedef unsigned long long u64;

using bf16x8 = __attribute__((ext_vector_type(8))) short;
using f32x4  = __attribute__((ext_vector_type(4))) float;
typedef float f4v __attribute__((ext_vector_type(4)));

#define NUNITS 31
#define WS_BIAS_OFF (NUNITS*8192)
#define NBIAS 1952

__device__ __forceinline__ u32 pk2(float a, float b){
    __hip_bfloat162 h = __float22bfloat162_rn(make_float2(a, b));
    union { __hip_bfloat162 h2; u32 u; } cv; cv.h2 = h; return cv.u;
}
__device__ __forceinline__ float b2f(u16 v){ return __uint_as_float(((u32)v) << 16); }
__device__ __forceinline__ int swch(int chunk, int key){ return (chunk & ~7) | ((chunk ^ key) & 7); }

// ---------------- weight pre-conversion (identical layout to R3/R4) ----------------
__global__ __launch_bounds__(256) void convert_weights(
    const float* __restrict__ enc_w,
    const float* __restrict__ q1, const float* __restrict__ k1,
    const float* __restrict__ v1, const float* __restrict__ o1,
    const float* __restrict__ q2, const float* __restrict__ k2,
    const float* __restrict__ v2, const float* __restrict__ o2,
    const float* __restrict__ gih, const float* __restrict__ ghh,
    const float* __restrict__ lin,
    const float* __restrict__ enc_b,
    const float* __restrict__ q1b, const float* __restrict__ k1b,
    const float* __restrict__ v1b, const float* __restrict__ o1b,
    const float* __restrict__ q2b, const float* __restrict__ k2b,
    const float* __restrict__ v2b, const float* __restrict__ o2b,
    const float* __restrict__ gbih, const float* __restrict__ gbhh,
    const float* __restrict__ linb,
    u16* __restrict__ dst)
{
    int idx = blockIdx.x*256 + threadIdx.x;
    if (idx < NUNITS*8192){
        int u = idx >> 13, rem = idx & 8191;
        int row = rem >> 6, ci = rem & 63;
        int p = ci >> 3, e = ci & 7;
        int lc = (((p ^ (row & 7)) & 7) << 3) | e;
        float val;
        if (u == 0){
            val = enc_w[row*64 + lc];
        } else if (u <= 16){
            int v = u - 1; int kh = v & 1;
            const float* s;
            switch (v >> 1){ case 0: s=q1; break; case 1: s=k1; break; case 2: s=v1; break;
                             case 3: s=o1; break; case 4: s=q2; break; case 5: s=k2; break;
                             case 6: s=v2; break; default: s=o2; }
            val = s[row*128 + kh*64 + lc];
        } else if (u <= 28){
            int v = u - 17; int kh = v & 1; int gate = v >> 2;
            const float* s = ((v >> 1) & 1) ? ghh : gih;
            val = s[(gate*128 + row)*128 + kh*64 + lc];
        } else {
            int kh = u - 29;
            val = (row < 20) ? lin[row*128 + kh*64 + lc] : 0.f;
        }
        __hip_bfloat16 hv = __float2bfloat16(val);
        union { __hip_bfloat16 h; u16 us; } cv; cv.h = hv;
        dst[idx] = cv.us;
    } else if (idx < NUNITS*8192 + NBIAS){
        int i = idx - NUNITS*8192;
        float val;
        if      (i < 128)  val = enc_b[i];
        else if (i < 256)  val = q1b[i-128];
        else if (i < 384)  val = k1b[i-256];
        else if (i < 512)  val = v1b[i-384];
        else if (i < 640)  val = o1b[i-512];
        else if (i < 768)  val = q2b[i-640];
        else if (i < 896)  val = k2b[i-768];
        else if (i < 1024) val = v2b[i-896];
        else if (i < 1152) val = o2b[i-1024];
        else if (i < 1536) val = gbih[i-1152];
        else if (i < 1920) val = gbhh[i-1536];
        else if (i < 1940) val = linb[i-1920];
        else               val = 0.f;
        ((float*)(dst + NUNITS*8192))[i] = val;
    }
}

// ---------------- pipeline primitives ----------------
#define BARX() do{ asm volatile("s_waitcnt lgkmcnt(0)" ::: "memory"); \
                   __builtin_amdgcn_s_barrier(); \
                   asm volatile("" ::: "memory"); }while(0)
#define WAITV(N) asm volatile("s_waitcnt vmcnt(" #N ")" ::: "memory")

template<int U>
__device__ __forceinline__ void issue_unit(const u16* Wu, u16* WBs, int tid){
    u16* slot = WBs + (U & 1) * 8192;
    const u16* src = Wu + U * 8192;
    #pragma unroll
    for (int t = 0; t < 4; t++){
        __builtin_amdgcn_global_load_lds(
            (const __attribute__((address_space(1))) void*)(src + t*2048 + tid*8),
            (__attribute__((address_space(3))) void*)(slot + t*2048 + tid*8),
            16, 0, 0);
    }
}
#define SLOTC(U) (WBs + ((U) & 1) * 8192)

template<int M,int N>
__device__ __forceinline__ void zacc(f32x4 (&a)[M][N]){
    #pragma unroll
    for (int i=0;i<M;i++)
        #pragma unroll
        for (int j=0;j<N;j++) a[i][j] = (f32x4){0.f,0.f,0.f,0.f};
}

// Y = X @ W^T (one 64-k half). Wave w owns oc-tiles {2w,2w+1}, all 4 token-tiles.
template<int KH>
__device__ __forceinline__ void wgemm(const u16* Wb, const u16* X,
                                      int w, int c, int g, f32x4 (&acc)[2][4]){
    const int key = c & 7;
    #pragma unroll
    for (int kk = 0; kk < 2; kk++){
        const int pw = (kk*4 + g) ^ key;
        bf16x8 a[2];
        #pragma unroll
        for (int i = 0; i < 2; i++)
            a[i] = *(const bf16x8*)(Wb + ((w*2+i)*16 + c)*64 + pw*8);
        #pragma unroll
        for (int j = 0; j < 4; j++){
            bf16x8 b = *(const bf16x8*)(X + (j*16 + c)*128 + (KH*8 + pw)*8);
            #pragma unroll
            for (int i = 0; i < 2; i++)
                acc[i][j] = __builtin_amdgcn_mfma_f32_16x16x32_bf16(a[i], b, acc[i][j], 0,0,0);
        }
    }
}

// V-GEMM: out[token][vcol]; wave w owns vcol-tiles {2w,2w+1}, all 4 token-tiles.
template<int KH>
__device__ __forceinline__ void vgemm(const u16* Wb, const u16* X,
                                      int w, int c, int g, f32x4 (&acc)[4][2]){
    const int key = c & 7;
    #pragma unroll
    for (int kk = 0; kk < 2; kk++){
        const int pw = (kk*4 + g) ^ key;
        bf16x8 a[4];
        #pragma unroll
        for (int i = 0; i < 4; i++)
            a[i] = *(const bf16x8*)(X + ((i*16 + c)*128) + (KH*8 + pw)*8);
        #pragma unroll
        for (int j = 0; j < 2; j++){
            bf16x8 b = *(const bf16x8*)(Wb + ((w*2+j)*16 + c)*64 + pw*8);
            #pragma unroll
            for (int i = 0; i < 4; i++)
                acc[i][j] = __builtin_amdgcn_mfma_f32_16x16x32_bf16(a[i], b, acc[i][j], 0,0,0);
        }
    }
}

__device__ __forceinline__ void epiW(f32x4 (&acc)[2][4], float4 bv0, float4 bv1,
                                     u16* dst, int w, int c, int g){
    const int key = c & 7;
    #pragma unroll
    for (int i = 0; i < 2; i++){
        float4 bv = i ? bv1 : bv0;
        const int col0 = (w*2+i)*16 + g*4;
        const int coff = swch(col0>>3, key)*8 + (col0&7);
        #pragma unroll
        for (int j = 0; j < 4; j++){
            int row = j*16 + c;
            float v0 = fmaxf(acc[i][j][0]+bv.x, 0.f);
            float v1 = fmaxf(acc[i][j][1]+bv.y, 0.f);
            float v2 = fmaxf(acc[i][j][2]+bv.z, 0.f);
            float v3 = fmaxf(acc[i][j][3]+bv.w, 0.f);
            uint2 o; o.x = pk2(v0,v1); o.y = pk2(v2,v3);
            *(uint2*)(dst + row*128 + coff) = o;
        }
    }
}

// ---------------- one MHA layer (template: all unit indices compile-time) ----------------
template<int LAYER>
__device__ __forceinline__ void mha_layer(const u16* Wu, u16* WBs,
                                          u16* ACT, u16* QXp, u16* KPp,
                                          const float* wsb, const float* h0, size_t rowbase,
                                          int tid, int w, int c, int g, const u64* mbits)
{
    constexpr int UB = 1 + LAYER*8;
    constexpr int BB = 128 + LAYER*512;
    const int key = c & 7;
    const int col00 = w*32 + g*4;
    const int col01 = col00 + 16;
    f32x4 acc[2][4];

    // ---- Q (units UB, UB+1) -> QXp ----
    BARX();
    float4 bq0 = *(const float4*)(wsb + BB + col00);
    float4 bq1 = *(const float4*)(wsb + BB + col01);
    issue_unit<UB+1>(Wu, WBs, tid);
    WAITV(4); BARX();
    zacc(acc); wgemm<0>(SLOTC(UB), ACT, w, c, g, acc);
    BARX(); issue_unit<UB+2>(Wu, WBs, tid); WAITV(4); BARX();
    wgemm<1>(SLOTC(UB+1), ACT, w, c, g, acc);
    epiW(acc, bq0, bq1, QXp, w, c, g);

    // ---- K (units UB+2, UB+3) -> KPp ----
    BARX();
    float4 bk0 = *(const float4*)(wsb + BB + 128 + col00);
    float4 bk1 = *(const float4*)(wsb + BB + 128 + col01);
    issue_unit<UB+3>(Wu, WBs, tid);
    WAITV(4); BARX();
    zacc(acc); wgemm<0>(SLOTC(UB+2), ACT, w, c, g, acc);
    BARX(); issue_unit<UB+4>(Wu, WBs, tid); WAITV(4); BARX();
    wgemm<1>(SLOTC(UB+3), ACT, w, c, g, acc);
    epiW(acc, bk0, bk1, KPp, w, c, g);

    // ---- V (units UB+4, UB+5) -> registers ----
    f32x4 vacc[4][2];
    BARX();
    float bv0 = wsb[BB + 256 + w*32 + c];
    float bv1 = wsb[BB + 256 + w*32 + 16 + c];
    issue_unit<UB+5>(Wu, WBs, tid);
    WAITV(4); BARX();
    zacc(vacc); vgemm<0>(SLOTC(UB+4), ACT, w, c, g, vacc);
    BARX(); issue_unit<UB+6>(Wu, WBs, tid); WAITV(4); BARX();
    vgemm<1>(SLOTC(UB+5), ACT, w, c, g, vacc);

    BARX();   // all ACT reads done -> overwrite with V^T [128 vcol][64 tok]
    #pragma unroll
    for (int j = 0; j < 2; j++){
        int vrow = w*32 + j*16 + c;
        float bv = j ? bv1 : bv0;
        #pragma unroll
        for (int i = 0; i < 4; i++){
            int kk = i >> 1, p = i & 1;
            float v0 = fmaxf(vacc[i][j][0]+bv, 0.f);
            float v1 = fmaxf(vacc[i][j][1]+bv, 0.f);
            float v2 = fmaxf(vacc[i][j][2]+bv, 0.f);
            float v3 = fmaxf(vacc[i][j][3]+bv, 0.f);
            uint2 o; o.x = pk2(v0,v1); o.y = pk2(v2,v3);
            *(uint2*)(ACT + vrow*64 + swch(kk*4+g, key)*8 + p*4) = o;
        }
    }

    // ---- scores: mfma(K, Q) -> lane c = q-row, (g,r) = k-token ----
    const int h = w;
    f32x4 sc[4][4];
    {
        bf16x8 kf[4];
        #pragma unroll
        for (int kt = 0; kt < 4; kt++)
            kf[kt] = *(const bf16x8*)(KPp + (kt*16 + c)*128 + swch(h*4+g, key)*8);
        #pragma unroll
        for (int qt = 0; qt < 4; qt++){
            bf16x8 qf = *(const bf16x8*)(QXp + (qt*16 + c)*128 + swch(h*4+g, key)*8);
            #pragma unroll
            for (int kt = 0; kt < 4; kt++){
                f32x4 z4 = (f32x4){0.f,0.f,0.f,0.f};
                sc[qt][kt] = __builtin_amdgcn_mfma_f32_16x16x32_bf16(kf[kt], qf, z4, 0,0,0);
            }
        }
    }
    BARX();   // Q/K reads + V^T writes complete; KPp dead after this point

    // T14 split: issue h0 loads now (LAYER 1 only); latency hides under softmax+PV
    f4v hr[8];
    if (LAYER == 1){
        const float* hp = h0 + (rowbase + (tid>>2))*128 + (tid&3)*32;
        #pragma unroll
        for (int t = 0; t < 8; t++)
            hr[t] = __builtin_nontemporal_load((const f4v*)(hp + t*4));
    }

    {   // in-register masked softmax + PV
        u32 pp[4][4][2];
        #pragma unroll
        for (int qt = 0; qt < 4; qt++){
            u64 mb = mbits[qt];
            float mx = -1e30f;
            #pragma unroll
            for (int kt = 0; kt < 4; kt++)
                #pragma unroll
                for (int r = 0; r < 4; r++){
                    float s = sc[qt][kt][r] * 0.17677669529663687f;
                    s = ((mb >> (kt*16 + g*4 + r)) & 1ull) ? s : -1e30f;
                    sc[qt][kt][r] = s;
                    mx = fmaxf(mx, s);
                }
            mx = fmaxf(mx, __shfl_xor(mx, 16));
            mx = fmaxf(mx, __shfl_xor(mx, 32));
            float sum = 0.f;
            #pragma unroll
            for (int kt = 0; kt < 4; kt++)
                #pragma unroll
                for (int r = 0; r < 4; r++){
                    float e = __expf(sc[qt][kt][r] - mx);
                    sc[qt][kt][r] = e; sum += e;
                }
            sum += __shfl_xor(sum, 16);
            sum += __shfl_xor(sum, 32);
            float inv = 1.f / sum;
            #pragma unroll
            for (int kt = 0; kt < 4; kt++){
                pp[qt][kt][0] = pk2(sc[qt][kt][0]*inv, sc[qt][kt][1]*inv);
                pp[qt][kt][1] = pk2(sc[qt][kt][2]*inv, sc[qt][kt][3]*inv);
            }
        }
        #pragma unroll
        for (int dt = 0; dt < 2; dt++){
            f32x4 pa[4];
            #pragma unroll
            for (int qt = 0; qt < 4; qt++) pa[qt] = (f32x4){0.f,0.f,0.f,0.f};
            #pragma unroll
            for (int kk = 0; kk < 2; kk++){
                bf16x8 vt = *(const bf16x8*)(ACT + (h*32 + dt*16 + c)*64 + ((kk*4+g)^key)*8);
                #pragma unroll
                for (int qt = 0; qt < 4; qt++){
                    union { u32 u4[4]; bf16x8 v8; } bbv;
                    bbv.u4[0]=pp[qt][kk*2][0];   bbv.u4[1]=pp[qt][kk*2][1];
                    bbv.u4[2]=pp[qt][kk*2+1][0]; bbv.u4[3]=pp[qt][kk*2+1][1];
                    pa[qt] = __builtin_amdgcn_mfma_f32_16x16x32_bf16(vt, bbv.v8, pa[qt], 0,0,0);
                }
            }
            #pragma unroll
            for (int qt = 0; qt < 4; qt++){
                int col = h*32 + dt*16 + g*4;
                uint2 o; o.x = pk2(pa[qt][0], pa[qt][1]); o.y = pk2(pa[qt][2], pa[qt][3]);
                *(uint2*)(QXp + (qt*16 + c)*128 + swch(col>>3, key)*8 + (col&7)) = o;
            }
        }
    }

    // T14 write-late: h0 bf16 -> KPp (dead after scores)
    if (LAYER == 1){
        int hrow = tid >> 2, seg = tid & 3;
        #pragma unroll
        for (int cc = 0; cc < 4; cc++){
            int p = seg*4 + cc;
            int ps = (p & 8) | ((p ^ (hrow & 7)) & 7);
            f4v fa = hr[cc*2], fb = hr[cc*2+1];
            uint4 o; o.x = pk2(fa.x,fa.y); o.y = pk2(fa.z,fa.w);
            o.z = pk2(fb.x,fb.y); o.w = pk2(fb.z,fb.w);
            *(uint4*)(KPp + hrow*128 + ps*8) = o;
        }
    }

    // ---- O-projection (units UB+6, UB+7): ACT = relu(X1 @ Wo^T + b) ----
    BARX();
    float4 bo0 = *(const float4*)(wsb + BB + 384 + col00);
    float4 bo1 = *(const float4*)(wsb + BB + 384 + col01);
    issue_unit<UB+7>(Wu, WBs, tid);
    WAITV(4); BARX();
    zacc(acc); wgemm<0>(SLOTC(UB+6), QXp, w, c, g, acc);
    BARX(); issue_unit<UB+8>(Wu, WBs, tid); WAITV(4); BARX();
    wgemm<1>(SLOTC(UB+7), QXp, w, c, g, acc);
    epiW(acc, bo0, bo1, ACT, w, c, g);
}

// ---------------- main fused kernel: 1 batch item / block, 256 threads ----------------
__global__ __launch_bounds__(256, 2) void drgn_pipe(
    const float* __restrict__ x, const int* __restrict__ maskg,
    const float* __restrict__ h0, const u16* __restrict__ W16,
    float* __restrict__ out_qs, float* __restrict__ out_h3)
{
    __shared__ __align__(16) u16 SMEM[40960];   // exactly 81920 B -> 2 blocks/CU
    u16* ACT = SMEM;                 // [64][128] acts / [128][64] V^T / h3
    u16* QXp = SMEM + 8192;          // x-in / Q / X1
    u16* KPp = SMEM + 16384;         // K / h0-bf16 (transient: mask u64[64] at start)
    u16* WBs = SMEM + 24576;         // 2 x 16KB weight ring

    const int tid = threadIdx.x;
    const int w = tid >> 6, lane = tid & 63;
    const int c = lane & 15, g = lane >> 4;
    const int key = c & 7;
    const size_t rowbase = (size_t)blockIdx.x * 64;
    const u16* Wu = W16;
    const float* wsb = (const float*)(W16 + WS_BIAS_OFF);
    const int col00 = w*32 + g*4;
    const int col01 = col00 + 16;

    // ---- prologue: mask bits -> regs (via KP transient), x -> QX bf16 ----
    u64* MrowT = (u64*)KPp;
    #pragma unroll 4
    for (int rr = 0; rr < 16; rr++){
        int row = w*16 + rr;
        int mv = __builtin_nontemporal_load(maskg + (rowbase + row)*64 + lane);
        u64 bits = __ballot(mv != 0);
        if (lane == 0) MrowT[row] = bits;
    }
    for (int i = tid; i < 512; i += 256){
        int row = i >> 3, p = i & 7;
        int lc = (p ^ (row & 7)) & 7;
        const float* sp = x + (rowbase + row)*64 + lc*8;
        f4v f0 = __builtin_nontemporal_load((const f4v*)sp);
        f4v f1 = __builtin_nontemporal_load((const f4v*)(sp + 4));
        uint4 o; o.x = pk2(f0.x,f0.y); o.y = pk2(f0.z,f0.w);
        o.z = pk2(f1.x,f1.y); o.w = pk2(f1.z,f1.w);
        *(uint4*)(QXp + row*128 + p*8) = o;
    }
    __syncthreads();
    u64 mbits[4];
    #pragma unroll
    for (int qt = 0; qt < 4; qt++) mbits[qt] = MrowT[qt*16 + c];

    issue_unit<0>(Wu, WBs, tid);

    // ---- encoder (unit 0): ACT = relu(x @ enc^T + b) ----
    {
        f32x4 acc[2][4];
        BARX();
        float4 b0 = *(const float4*)(wsb + col00);
        float4 b1 = *(const float4*)(wsb + col01);
        issue_unit<1>(Wu, WBs, tid);
        WAITV(4); BARX();
        zacc(acc);
        wgemm<0>(SLOTC(0), QXp, w, c, g, acc);
        epiW(acc, b0, b1, ACT, w, c, g);
    }

    // ---- two MHA layers ----
    mha_layer<0>(Wu, WBs, ACT, QXp, KPp, wsb, h0, rowbase, tid, w, c, g, mbits);
    mha_layer<1>(Wu, WBs, ACT, QXp, KPp, wsb, h0, rowbase, tid, w, c, g, mbits);

    // ---- GRU: ACT = h2, KPp = h0(bf16). Gates explicit, 1-deep ring. ----
    float rrA[2][4][4], zzA[2][4][4];
    {   // gate r: aI units 17,18; aH units 19,20
        f32x4 aI[2][4], aH[2][4];
        BARX(); issue_unit<18>(Wu, WBs, tid); WAITV(4); BARX();
        zacc(aI); wgemm<0>(SLOTC(17), ACT, w, c, g, aI);
        BARX(); issue_unit<19>(Wu, WBs, tid); WAITV(4); BARX();
        wgemm<1>(SLOTC(18), ACT, w, c, g, aI);
        BARX();
        float4 bi0 = *(const float4*)(wsb + 1152 + col00);
        float4 bi1 = *(const float4*)(wsb + 1152 + col01);
        float4 bh0 = *(const float4*)(wsb + 1536 + col00);
        float4 bh1 = *(const float4*)(wsb + 1536 + col01);
        issue_unit<20>(Wu, WBs, tid); WAITV(4); BARX();
        zacc(aH); wgemm<0>(SLOTC(19), KPp, w, c, g, aH);
        BARX(); issue_unit<21>(Wu, WBs, tid); WAITV(4); BARX();
        wgemm<1>(SLOTC(20), KPp, w, c, g, aH);
        #pragma unroll
        for (int i = 0; i < 2; i++){
            float4 bi = i ? bi1 : bi0; float4 bh = i ? bh1 : bh0;
            #pragma unroll
            for (int j = 0; j < 4; j++)
                #pragma unroll
                for (int r = 0; r < 4; r++)
                    rrA[i][j][r] = 1.f/(1.f + __expf(-(aI[i][j][r] + (&bi.x)[r] + aH[i][j][r] + (&bh.x)[r])));
        }
    }
    {   // gate z: aI units 21,22; aH units 23,24
        f32x4 aI[2][4], aH[2][4];
        BARX(); issue_unit<22>(Wu, WBs, tid); WAITV(4); BARX();
        zacc(aI); wgemm<0>(SLOTC(21), ACT, w, c, g, aI);
        BARX(); issue_unit<23>(Wu, WBs, tid); WAITV(4); BARX();
        wgemm<1>(SLOTC(22), ACT, w, c, g, aI);
        BARX();
        float4 bi0 = *(const float4*)(wsb + 1152 + 128 + col00);
        float4 bi1 = *(const float4*)(wsb + 1152 + 128 + col01);
        float4 bh0 = *(const float4*)(wsb + 1536 + 128 + col00);
        float4 bh1 = *(const float4*)(wsb + 1536 + 128 + col01);
        issue_unit<24>(Wu, WBs, tid); WAITV(4); BARX();
        zacc(aH); wgemm<0>(SLOTC(23), KPp, w, c, g, aH);
        BARX(); issue_unit<25>(Wu, WBs, tid); WAITV(4); BARX();
        wgemm<1>(SLOTC(24), KPp, w, c, g, aH);
        #pragma unroll
        for (int i = 0; i < 2; i++){
            float4 bi = i ? bi1 : bi0; float4 bh = i ? bh1 : bh0;
            #pragma unroll
            for (int j = 0; j < 4; j++)
                #pragma unroll
                for (int r = 0; r < 4; r++)
                    zzA[i][j][r] = 1.f/(1.f + __expf(-(aI[i][j][r] + (&bi.x)[r] + aH[i][j][r] + (&bh.x)[r])));
        }
    }
    {   // gate n: aI units 25,26; aH units 27,28; combine + h3 stores
        f32x4 aI[2][4], aH[2][4];
        BARX(); issue_unit<26>(Wu, WBs, tid); WAITV(4); BARX();
        zacc(aI); wgemm<0>(SLOTC(25), ACT, w, c, g, aI);
        BARX(); issue_unit<27>(Wu, WBs, tid); WAITV(4); BARX();
        wgemm<1>(SLOTC(26), ACT, w, c, g, aI);
        BARX();
        float4 bi0 = *(const float4*)(wsb + 1152 + 256 + col00);
        float4 bi1 = *(const float4*)(wsb + 1152 + 256 + col01);
        float4 bh0 = *(const float4*)(wsb + 1536 + 256 + col00);
        float4 bh1 = *(const float4*)(wsb + 1536 + 256 + col01);
        issue_unit<28>(Wu, WBs, tid); WAITV(4); BARX();
        zacc(aH); wgemm<0>(SLOTC(27), KPp, w, c, g, aH);
        BARX(); issue_unit<29>(Wu, WBs, tid); WAITV(4); BARX();
        wgemm<1>(SLOTC(28), KPp, w, c, g, aH);

        #pragma unroll
        for (int i = 0; i < 2; i++){
            float4 bi = i ? bi1 : bi0; float4 bh = i ? bh1 : bh0;
            int col0 = w*32 + i*16 + g*4;
            int coff = swch(col0>>3, key)*8 + (col0&7);
            #pragma unroll
            for (int j = 0; j < 4; j++){
                int row = j*16 + c;
                uint2 hv = *(const uint2*)(KPp + row*128 + coff);
                float h0v[4] = { b2f((u16)(hv.x & 0xffffu)), b2f((u16)(hv.x >> 16)),
                                 b2f((u16)(hv.y & 0xffffu)), b2f((u16)(hv.y >> 16)) };
                f4v h3o;
                #pragma unroll
                for (int r = 0; r < 4; r++){
                    float xn = aI[i][j][r] + (&bi.x)[r] + rrA[i][j][r]*(aH[i][j][r] + (&bh.x)[r]);
                    float e2 = __expf(-2.f*fabsf(xn));
                    float th = (1.f - e2)/(1.f + e2);
                    th = (xn >= 0.f) ? th : -th;
                    float zv = zzA[i][j][r];
                    h3o[r] = (1.f - zv)*th + zv*h0v[r];
                }
                uint2 o; o.x = pk2(h3o[0],h3o[1]); o.y = pk2(h3o[2],h3o[3]);
                *(uint2*)(ACT + row*128 + coff) = o;   // h3 bf16 -> ACT (for qs GEMM)
                __builtin_nontemporal_store(h3o, (f4v*)(out_h3 + (rowbase + row)*128 + col0));
            }
        }
    }

    // ---- final linear (units 29,30) + qs stores ----
    {
        f32x4 qa[2][4];
        BARX();
        float4 lb0 = (col00 < 20) ? *(const float4*)(wsb + 1920 + col00) : (float4){0.f,0.f,0.f,0.f};
        float4 lb1 = (col01 < 20) ? *(const float4*)(wsb + 1920 + col01) : (float4){0.f,0.f,0.f,0.f};
        issue_unit<30>(Wu, WBs, tid);
        WAITV(4); BARX();
        zacc(qa); wgemm<0>(SLOTC(29), ACT, w, c, g, qa);
        BARX(); WAITV(0); BARX();
        wgemm<1>(SLOTC(30), ACT, w, c, g, qa);

        #pragma unroll
        for (int i = 0; i < 2; i++){
            int col0 = w*32 + i*16 + g*4;
            if (col0 < 20){
                float4 lb = i ? lb1 : lb0;
                #pragma unroll
                for (int j = 0; j < 4; j++){
                    int row = j*16 + c;
                    f4v o;
                    o.x = qa[i][j][0]+lb.x; o.y = qa[i][j][1]+lb.y;
                    o.z = qa[i][j][2]+lb.z; o.w = qa[i][j][3]+lb.w;
                    __builtin_nontemporal_store(o, (f4v*)(out_qs + (rowbase + row)*20 + col0));
                }
            }
        }
    }
}

extern "C" void kernel_launch(void* const* d_in, const int* in_sizes, int n_in,
                              void* d_out, int out_size, void* d_ws, size_t ws_size,
                              hipStream_t stream) {
    const float* x     = (const float*)d_in[0];
    const int*   mask  = (const int*)  d_in[1];
    const float* h0    = (const float*)d_in[2];
    const float* enc_w = (const float*)d_in[3];
    const float* enc_b = (const float*)d_in[4];
    const float* q1_w  = (const float*)d_in[5];  const float* q1_b = (const float*)d_in[6];
    const float* k1_w  = (const float*)d_in[7];  const float* k1_b = (const float*)d_in[8];
    const float* v1_w  = (const float*)d_in[9];  const float* v1_b = (const float*)d_in[10];
    const float* o1_w  = (const float*)d_in[11]; const float* o1_b = (const float*)d_in[12];
    const float* q2_w  = (const float*)d_in[13]; const float* q2_b = (const float*)d_in[14];
    const float* k2_w  = (const float*)d_in[15]; const float* k2_b = (const float*)d_in[16];
    const float* v2_w  = (const float*)d_in[17]; const float* v2_b = (const float*)d_in[18];
    const float* o2_w  = (const float*)d_in[19]; const float* o2_b = (const float*)d_in[20];
    const float* gwih  = (const float*)d_in[21]; const float* gwhh = (const float*)d_in[22];
    const float* gbih  = (const float*)d_in[23]; const float* gbhh = (const float*)d_in[24];
    const float* lin_w = (const float*)d_in[25]; const float* lin_b = (const float*)d_in[26];

    const int bs = in_sizes[0] / (64 * 64);           // 4096
    float* out_qs = (float*)d_out;
    float* out_h3 = out_qs + (size_t)bs * 64 * 20;
    u16* W16 = (u16*)d_ws;

    const int total = NUNITS*8192 + NBIAS;
    hipLaunchKernelGGL(convert_weights, dim3((total + 255) / 256), dim3(256), 0, stream,
                       enc_w, q1_w, k1_w, v1_w, o1_w, q2_w, k2_w, v2_w, o2_w,
                       gwih, gwhh, lin_w,
                       enc_b, q1_b, k1_b, v1_b, o1_b, q2_b, k2_b, v2_b, o2_b,
                       gbih, gbhh, lin_b, W16);
    hipLaunchKernelGGL(drgn_pipe, dim3(bs), dim3(256), 0, stream,
                       x, mask, h0, W16, out_qs, out_h3);
}

// Round 6
// 365.717 us; speedup vs baseline: 1.5863x; 1.0605x over previous
//
#include <hip/hip_runtime.h>
#include <hip/hip_bf16.h>

typedef unsigned int u32;
typedef unsigned short u16;
typedef unsigned long long u64;

using bf16x8 = __attribute__((ext_vector_type(8))) short;
using f32x4  = __attribute__((ext_vector_type(4))) float;
typedef float f4v __attribute__((ext_vector_type(4)));

#define NUNITS 31
#define WS_BIAS_OFF (NUNITS*8192)
#define NBIAS 1952

__device__ __forceinline__ u32 pk2(float a, float b){
    __hip_bfloat162 h = __float22bfloat162_rn(make_float2(a, b));
    union { __hip_bfloat162 h2; u32 u; } cv; cv.h2 = h; return cv.u;
}
__device__ __forceinline__ float b2f(u16 v){ return __uint_as_float(((u32)v) << 16); }
__device__ __forceinline__ int swch(int chunk, int key){ return (chunk & ~7) | ((chunk ^ key) & 7); }

// ---------------- weight pre-conversion: NEW unit order for X-fragment reuse ----------------
// u0: enc | layer L (base 1+8L): q0,k0,v0,q1,k1,v1,o0,o1
// GRU (17..28): r_ih0,z_ih0,r_ih1,z_ih1, r_hh0,z_hh0,r_hh1,z_hh1, n_ih0,n_ih1,n_hh0,n_hh1
// u29,u30: lin kh0, kh1
__global__ __launch_bounds__(256) void convert_weights(
    const float* __restrict__ enc_w,
    const float* __restrict__ q1, const float* __restrict__ k1,
    const float* __restrict__ v1, const float* __restrict__ o1,
    const float* __restrict__ q2, const float* __restrict__ k2,
    const float* __restrict__ v2, const float* __restrict__ o2,
    const float* __restrict__ gih, const float* __restrict__ ghh,
    const float* __restrict__ lin,
    const float* __restrict__ enc_b,
    const float* __restrict__ q1b, const float* __restrict__ k1b,
    const float* __restrict__ v1b, const float* __restrict__ o1b,
    const float* __restrict__ q2b, const float* __restrict__ k2b,
    const float* __restrict__ v2b, const float* __restrict__ o2b,
    const float* __restrict__ gbih, const float* __restrict__ gbhh,
    const float* __restrict__ linb,
    u16* __restrict__ dst)
{
    int idx = blockIdx.x*256 + threadIdx.x;
    if (idx < NUNITS*8192){
        int u = idx >> 13, rem = idx & 8191;
        int row = rem >> 6, ci = rem & 63;
        int p = ci >> 3, e = ci & 7;
        int lc = (((p ^ (row & 7)) & 7) << 3) | e;
        float val;
        if (u == 0){
            val = enc_w[row*64 + lc];
        } else if (u <= 16){
            int v = u - 1; int L = v >> 3; int r8 = v & 7;
            int mat, kh;
            if (r8 < 6){ mat = r8 % 3; kh = r8 / 3; } else { mat = 3; kh = r8 - 6; }
            const float* s;
            if (L == 0){ s = (mat==0)?q1:(mat==1)?k1:(mat==2)?v1:o1; }
            else       { s = (mat==0)?q2:(mat==1)?k2:(mat==2)?v2:o2; }
            val = s[row*128 + kh*64 + lc];
        } else if (u <= 28){
            int v = u - 17;
            int gate, kh; const float* s;
            if (v < 8){ gate = v & 1; kh = (v >> 1) & 1; s = (v >= 4) ? ghh : gih; }
            else      { int w8 = v - 8; gate = 2; kh = w8 & 1; s = (w8 >= 2) ? ghh : gih; }
            val = s[(gate*128 + row)*128 + kh*64 + lc];
        } else {
            int kh = u - 29;
            val = (row < 20) ? lin[row*128 + kh*64 + lc] : 0.f;
        }
        __hip_bfloat16 hv = __float2bfloat16(val);
        union { __hip_bfloat16 h; u16 us; } cv; cv.h = hv;
        dst[idx] = cv.us;
    } else if (idx < NUNITS*8192 + NBIAS){
        int i = idx - NUNITS*8192;
        float val;
        if      (i < 128)  val = enc_b[i];
        else if (i < 256)  val = q1b[i-128];
        else if (i < 384)  val = k1b[i-256];
        else if (i < 512)  val = v1b[i-384];
        else if (i < 640)  val = o1b[i-512];
        else if (i < 768)  val = q2b[i-640];
        else if (i < 896)  val = k2b[i-768];
        else if (i < 1024) val = v2b[i-896];
        else if (i < 1152) val = o2b[i-1024];
        else if (i < 1536) val = gbih[i-1152];
        else if (i < 1920) val = gbhh[i-1536];
        else if (i < 1940) val = linb[i-1920];
        else               val = 0.f;
        ((float*)(dst + NUNITS*8192))[i] = val;
    }
}

// ---------------- pipeline primitives ----------------
#define BARX() do{ asm volatile("s_waitcnt lgkmcnt(0)" ::: "memory"); \
                   __builtin_amdgcn_s_barrier(); \
                   asm volatile("" ::: "memory"); }while(0)
#define WAITV(N) asm volatile("s_waitcnt vmcnt(" #N ")" ::: "memory")

template<int U>
__device__ __forceinline__ void issue_unit(const u16* Wu, u16* WBs, int tid){
    u16* slot = WBs + (U & 1) * 8192;
    const u16* src = Wu + U * 8192;
    #pragma unroll
    for (int t = 0; t < 4; t++){
        __builtin_amdgcn_global_load_lds(
            (const __attribute__((address_space(1))) void*)(src + t*2048 + tid*8),
            (__attribute__((address_space(3))) void*)(slot + t*2048 + tid*8),
            16, 0, 0);
    }
}
#define SLOTC(U) (WBs + ((U) & 1) * 8192)

// phase entry: barrier (prev consume done) -> prefetch U+1 -> wait U landed -> barrier
template<int U, bool ISSUE>
__device__ __forceinline__ void phase_pre(const u16* Wu, u16* WBs, int tid){
    BARX();
    if constexpr (ISSUE){
        issue_unit<U+1>(Wu, WBs, tid);
        WAITV(4);
    } else {
        WAITV(0);
    }
    BARX();
}

template<int M,int N>
__device__ __forceinline__ void zacc(f32x4 (&a)[M][N]){
    #pragma unroll
    for (int i=0;i<M;i++)
        #pragma unroll
        for (int j=0;j<N;j++) a[i][j] = (f32x4){0.f,0.f,0.f,0.f};
}

// X fragments for one 64-k half: [tok-tile][kk], persisted in VGPRs across phases
struct XF { bf16x8 f[4][2]; };

__device__ __forceinline__ void loadX(XF& xf, const u16* X, int kh, int c, int g){
    const int key = c & 7;
    #pragma unroll
    for (int kk = 0; kk < 2; kk++){
        const int pw = (kk*4 + g) ^ key;
        #pragma unroll
        for (int j = 0; j < 4; j++)
            xf.f[j][kk] = *(const bf16x8*)(X + (j*16 + c)*128 + (kh*8 + pw)*8);
    }
}

// Y = X @ W^T : wave owns oc-tiles {2w,2w+1}, X from registers
__device__ __forceinline__ void wgemmR(const u16* Wb, const XF& xf,
                                       int w, int c, int g, f32x4 (&acc)[2][4]){
    const int key = c & 7;
    __builtin_amdgcn_s_setprio(1);
    #pragma unroll
    for (int kk = 0; kk < 2; kk++){
        const int pw = (kk*4 + g) ^ key;
        bf16x8 a0 = *(const bf16x8*)(Wb + ((w*2+0)*16 + c)*64 + pw*8);
        bf16x8 a1 = *(const bf16x8*)(Wb + ((w*2+1)*16 + c)*64 + pw*8);
        #pragma unroll
        for (int j = 0; j < 4; j++){
            acc[0][j] = __builtin_amdgcn_mfma_f32_16x16x32_bf16(a0, xf.f[j][kk], acc[0][j], 0,0,0);
            acc[1][j] = __builtin_amdgcn_mfma_f32_16x16x32_bf16(a1, xf.f[j][kk], acc[1][j], 0,0,0);
        }
    }
    __builtin_amdgcn_s_setprio(0);
}

// V-GEMM: out[token][vcol]; X frags are the A operand (same lane layout)
__device__ __forceinline__ void vgemmR(const u16* Wb, const XF& xf,
                                       int w, int c, int g, f32x4 (&acc)[4][2]){
    const int key = c & 7;
    __builtin_amdgcn_s_setprio(1);
    #pragma unroll
    for (int kk = 0; kk < 2; kk++){
        const int pw = (kk*4 + g) ^ key;
        bf16x8 b0 = *(const bf16x8*)(Wb + ((w*2+0)*16 + c)*64 + pw*8);
        bf16x8 b1 = *(const bf16x8*)(Wb + ((w*2+1)*16 + c)*64 + pw*8);
        #pragma unroll
        for (int i = 0; i < 4; i++){
            acc[i][0] = __builtin_amdgcn_mfma_f32_16x16x32_bf16(xf.f[i][kk], b0, acc[i][0], 0,0,0);
            acc[i][1] = __builtin_amdgcn_mfma_f32_16x16x32_bf16(xf.f[i][kk], b1, acc[i][1], 0,0,0);
        }
    }
    __builtin_amdgcn_s_setprio(0);
}

__device__ __forceinline__ void epiW(f32x4 (&acc)[2][4], float4 bv0, float4 bv1,
                                     u16* dst, int w, int c, int g){
    const int key = c & 7;
    #pragma unroll
    for (int i = 0; i < 2; i++){
        float4 bv = i ? bv1 : bv0;
        const int col0 = (w*2+i)*16 + g*4;
        const int coff = swch(col0>>3, key)*8 + (col0&7);
        #pragma unroll
        for (int j = 0; j < 4; j++){
            int row = j*16 + c;
            float v0 = fmaxf(acc[i][j][0]+bv.x, 0.f);
            float v1 = fmaxf(acc[i][j][1]+bv.y, 0.f);
            float v2 = fmaxf(acc[i][j][2]+bv.z, 0.f);
            float v3 = fmaxf(acc[i][j][3]+bv.w, 0.f);
            uint2 o; o.x = pk2(v0,v1); o.y = pk2(v2,v3);
            *(uint2*)(dst + row*128 + coff) = o;
        }
    }
}

// ---------------- one MHA layer ----------------
template<int LAYER>
__device__ __forceinline__ void mha_layer(const u16* Wu, u16* WBs,
                                          u16* ACT, u16* QXp, u16* KPp,
                                          const float* wsb, const float* h0, size_t rowbase,
                                          int tid, int w, int c, int g, const u64* mbits)
{
    constexpr int UB = 1 + LAYER*8;
    constexpr int BB = 128 + LAYER*512;
    const int key = c & 7;
    const int col00 = w*32 + g*4;
    const int col01 = col00 + 16;

    XF xf;
    f32x4 accQ[2][4], accK[2][4];
    f32x4 vacc[4][2];

    // kh0 group: q0, k0, v0 share xf
    phase_pre<UB+0, true>(Wu, WBs, tid);
    zacc(accQ); zacc(accK); zacc(vacc);
    loadX(xf, ACT, 0, c, g);
    wgemmR(SLOTC(UB+0), xf, w, c, g, accQ);

    phase_pre<UB+1, true>(Wu, WBs, tid);
    wgemmR(SLOTC(UB+1), xf, w, c, g, accK);

    phase_pre<UB+2, true>(Wu, WBs, tid);
    vgemmR(SLOTC(UB+2), xf, w, c, g, vacc);

    // kh1 group: q1, k1, v1
    float4 bq0 = *(const float4*)(wsb + BB + col00);
    float4 bq1 = *(const float4*)(wsb + BB + col01);
    phase_pre<UB+3, true>(Wu, WBs, tid);
    loadX(xf, ACT, 1, c, g);
    wgemmR(SLOTC(UB+3), xf, w, c, g, accQ);
    epiW(accQ, bq0, bq1, QXp, w, c, g);

    float4 bk0 = *(const float4*)(wsb + BB + 128 + col00);
    float4 bk1 = *(const float4*)(wsb + BB + 128 + col01);
    phase_pre<UB+4, true>(Wu, WBs, tid);
    wgemmR(SLOTC(UB+4), xf, w, c, g, accK);
    epiW(accK, bk0, bk1, KPp, w, c, g);

    float bv0 = wsb[BB + 256 + w*32 + c];
    float bv1 = wsb[BB + 256 + w*32 + 16 + c];
    phase_pre<UB+5, true>(Wu, WBs, tid);
    vgemmR(SLOTC(UB+5), xf, w, c, g, vacc);

    // V^T epilogue -> ACT [128 vcol][64 tok]; last ACT read was loadX at UB+3 (barriers since)
    #pragma unroll
    for (int j = 0; j < 2; j++){
        int vrow = w*32 + j*16 + c;
        float bv = j ? bv1 : bv0;
        #pragma unroll
        for (int i = 0; i < 4; i++){
            int kk = i >> 1, p = i & 1;
            float v0 = fmaxf(vacc[i][j][0]+bv, 0.f);
            float v1 = fmaxf(vacc[i][j][1]+bv, 0.f);
            float v2 = fmaxf(vacc[i][j][2]+bv, 0.f);
            float v3 = fmaxf(vacc[i][j][3]+bv, 0.f);
            uint2 o; o.x = pk2(v0,v1); o.y = pk2(v2,v3);
            *(uint2*)(ACT + vrow*64 + swch(kk*4+g, key)*8 + p*4) = o;
        }
    }

    // scores: mfma(K, Q) -> lane c = q-row, (g,r) = k-token
    const int h = w;
    f32x4 sc[4][4];
    {
        bf16x8 kf[4];
        #pragma unroll
        for (int kt = 0; kt < 4; kt++)
            kf[kt] = *(const bf16x8*)(KPp + (kt*16 + c)*128 + swch(h*4+g, key)*8);
        __builtin_amdgcn_s_setprio(1);
        #pragma unroll
        for (int qt = 0; qt < 4; qt++){
            bf16x8 qf = *(const bf16x8*)(QXp + (qt*16 + c)*128 + swch(h*4+g, key)*8);
            #pragma unroll
            for (int kt = 0; kt < 4; kt++){
                f32x4 z4 = (f32x4){0.f,0.f,0.f,0.f};
                sc[qt][kt] = __builtin_amdgcn_mfma_f32_16x16x32_bf16(kf[kt], qf, z4, 0,0,0);
            }
        }
        __builtin_amdgcn_s_setprio(0);
    }
    BARX();   // V^T writes + Q/K reads complete

    // T14: issue h0 loads (LAYER 1); latency hides under softmax+PV
    f4v hr[8];
    if (LAYER == 1){
        const float* hp = h0 + (rowbase + (tid>>2))*128 + (tid&3)*32;
        #pragma unroll
        for (int t = 0; t < 8; t++)
            hr[t] = __builtin_nontemporal_load((const f4v*)(hp + t*4));
    }

    {   // in-register masked softmax + PV
        u32 pp[4][4][2];
        #pragma unroll
        for (int qt = 0; qt < 4; qt++){
            u64 mb = mbits[qt];
            float mx = -1e30f;
            #pragma unroll
            for (int kt = 0; kt < 4; kt++)
                #pragma unroll
                for (int r = 0; r < 4; r++){
                    float s = sc[qt][kt][r] * 0.17677669529663687f;
                    s = ((mb >> (kt*16 + g*4 + r)) & 1ull) ? s : -1e30f;
                    sc[qt][kt][r] = s;
                    mx = fmaxf(mx, s);
                }
            mx = fmaxf(mx, __shfl_xor(mx, 16));
            mx = fmaxf(mx, __shfl_xor(mx, 32));
            float sum = 0.f;
            #pragma unroll
            for (int kt = 0; kt < 4; kt++)
                #pragma unroll
                for (int r = 0; r < 4; r++){
                    float e = __expf(sc[qt][kt][r] - mx);
                    sc[qt][kt][r] = e; sum += e;
                }
            sum += __shfl_xor(sum, 16);
            sum += __shfl_xor(sum, 32);
            float inv = 1.f / sum;
            #pragma unroll
            for (int kt = 0; kt < 4; kt++){
                pp[qt][kt][0] = pk2(sc[qt][kt][0]*inv, sc[qt][kt][1]*inv);
                pp[qt][kt][1] = pk2(sc[qt][kt][2]*inv, sc[qt][kt][3]*inv);
            }
        }
        #pragma unroll
        for (int dt = 0; dt < 2; dt++){
            f32x4 pa[4];
            #pragma unroll
            for (int qt = 0; qt < 4; qt++) pa[qt] = (f32x4){0.f,0.f,0.f,0.f};
            #pragma unroll
            for (int kk = 0; kk < 2; kk++){
                bf16x8 vt = *(const bf16x8*)(ACT + (h*32 + dt*16 + c)*64 + ((kk*4+g)^key)*8);
                __builtin_amdgcn_s_setprio(1);
                #pragma unroll
                for (int qt = 0; qt < 4; qt++){
                    union { u32 u4[4]; bf16x8 v8; } bbv;
                    bbv.u4[0]=pp[qt][kk*2][0];   bbv.u4[1]=pp[qt][kk*2][1];
                    bbv.u4[2]=pp[qt][kk*2+1][0]; bbv.u4[3]=pp[qt][kk*2+1][1];
                    pa[qt] = __builtin_amdgcn_mfma_f32_16x16x32_bf16(vt, bbv.v8, pa[qt], 0,0,0);
                }
                __builtin_amdgcn_s_setprio(0);
            }
            #pragma unroll
            for (int qt = 0; qt < 4; qt++){
                int col = h*32 + dt*16 + g*4;
                uint2 o; o.x = pk2(pa[qt][0], pa[qt][1]); o.y = pk2(pa[qt][2], pa[qt][3]);
                *(uint2*)(QXp + (qt*16 + c)*128 + swch(col>>3, key)*8 + (col&7)) = o;
            }
        }
    }

    // T14 write-late: h0 bf16 -> KPp (dead after scores)
    if (LAYER == 1){
        int hrow = tid >> 2, seg = tid & 3;
        #pragma unroll
        for (int cc = 0; cc < 4; cc++){
            int p = seg*4 + cc;
            int ps = (p & 8) | ((p ^ (hrow & 7)) & 7);
            f4v fa = hr[cc*2], fb = hr[cc*2+1];
            uint4 o; o.x = pk2(fa.x,fa.y); o.y = pk2(fa.z,fa.w);
            o.z = pk2(fb.x,fb.y); o.w = pk2(fb.z,fb.w);
            *(uint4*)(KPp + hrow*128 + ps*8) = o;
        }
    }

    // O-projection: ACT = relu(X1 @ Wo^T + b)
    f32x4 acc[2][4];
    phase_pre<UB+6, true>(Wu, WBs, tid);
    zacc(acc);
    loadX(xf, QXp, 0, c, g);
    wgemmR(SLOTC(UB+6), xf, w, c, g, acc);

    float4 bo0 = *(const float4*)(wsb + BB + 384 + col00);
    float4 bo1 = *(const float4*)(wsb + BB + 384 + col01);
    phase_pre<UB+7, true>(Wu, WBs, tid);
    loadX(xf, QXp, 1, c, g);
    wgemmR(SLOTC(UB+7), xf, w, c, g, acc);
    epiW(acc, bo0, bo1, ACT, w, c, g);
}

// ---------------- main fused kernel: 1 batch item / block, 256 threads ----------------
__global__ __launch_bounds__(256, 2) void drgn_pipe(
    const float* __restrict__ x, const int* __restrict__ maskg,
    const float* __restrict__ h0, const u16* __restrict__ W16,
    float* __restrict__ out_qs, float* __restrict__ out_h3)
{
    __shared__ __align__(16) u16 SMEM[40960];   // exactly 81920 B -> 2 blocks/CU
    u16* ACT = SMEM;                 // [64][128] acts / [128][64] V^T / h3
    u16* QXp = SMEM + 8192;          // x-in / Q / X1
    u16* KPp = SMEM + 16384;         // K / h0-bf16 (transient: mask u64[64] at start)
    u16* WBs = SMEM + 24576;         // 2 x 16KB weight ring

    const int tid = threadIdx.x;
    const int w = tid >> 6, lane = tid & 63;
    const int c = lane & 15, g = lane >> 4;
    const int key = c & 7;
    const size_t rowbase = (size_t)blockIdx.x * 64;
    const u16* Wu = W16;
    const float* wsb = (const float*)(W16 + WS_BIAS_OFF);
    const int col00 = w*32 + g*4;
    const int col01 = col00 + 16;

    // ---- prologue: mask bits -> regs (via KP transient), x -> QX bf16 ----
    u64* MrowT = (u64*)KPp;
    #pragma unroll 4
    for (int rr = 0; rr < 16; rr++){
        int row = w*16 + rr;
        int mv = __builtin_nontemporal_load(maskg + (rowbase + row)*64 + lane);
        u64 bits = __ballot(mv != 0);
        if (lane == 0) MrowT[row] = bits;
    }
    for (int i = tid; i < 512; i += 256){
        int row = i >> 3, p = i & 7;
        int lc = (p ^ (row & 7)) & 7;
        const float* sp = x + (rowbase + row)*64 + lc*8;
        f4v f0 = __builtin_nontemporal_load((const f4v*)sp);
        f4v f1 = __builtin_nontemporal_load((const f4v*)(sp + 4));
        uint4 o; o.x = pk2(f0.x,f0.y); o.y = pk2(f0.z,f0.w);
        o.z = pk2(f1.x,f1.y); o.w = pk2(f1.z,f1.w);
        *(uint4*)(QXp + row*128 + p*8) = o;
    }
    __syncthreads();
    u64 mbits[4];
    #pragma unroll
    for (int qt = 0; qt < 4; qt++) mbits[qt] = MrowT[qt*16 + c];

    issue_unit<0>(Wu, WBs, tid);

    // ---- encoder (unit 0): ACT = relu(x @ enc^T + b) ----
    {
        XF xf;
        f32x4 acc[2][4];
        float4 b0 = *(const float4*)(wsb + col00);
        float4 b1 = *(const float4*)(wsb + col01);
        phase_pre<0, true>(Wu, WBs, tid);
        zacc(acc);
        loadX(xf, QXp, 0, c, g);
        wgemmR(SLOTC(0), xf, w, c, g, acc);
        epiW(acc, b0, b1, ACT, w, c, g);
    }

    // ---- two MHA layers ----
    mha_layer<0>(Wu, WBs, ACT, QXp, KPp, wsb, h0, rowbase, tid, w, c, g, mbits);
    mha_layer<1>(Wu, WBs, ACT, QXp, KPp, wsb, h0, rowbase, tid, w, c, g, mbits);

    // ---- GRU: ACT = h2, KPp = h0(bf16). 2-way X sharing per k-half. ----
    // units: 17 r_ih0, 18 z_ih0, 19 r_ih1, 20 z_ih1, 21 r_hh0, 22 z_hh0,
    //        23 r_hh1, 24 z_hh1, 25 n_ih0, 26 n_ih1, 27 n_hh0, 28 n_hh1
    XF xf;
    float rrA[2][4][4], zzA[2][4][4];
    {
        f32x4 aIr[2][4], aIz[2][4], aHr[2][4], aHz[2][4];
        phase_pre<17, true>(Wu, WBs, tid);
        zacc(aIr); zacc(aIz);
        loadX(xf, ACT, 0, c, g);
        wgemmR(SLOTC(17), xf, w, c, g, aIr);
        phase_pre<18, true>(Wu, WBs, tid);
        wgemmR(SLOTC(18), xf, w, c, g, aIz);
        phase_pre<19, true>(Wu, WBs, tid);
        loadX(xf, ACT, 1, c, g);
        wgemmR(SLOTC(19), xf, w, c, g, aIr);
        phase_pre<20, true>(Wu, WBs, tid);
        wgemmR(SLOTC(20), xf, w, c, g, aIz);

        phase_pre<21, true>(Wu, WBs, tid);
        zacc(aHr); zacc(aHz);
        loadX(xf, KPp, 0, c, g);
        wgemmR(SLOTC(21), xf, w, c, g, aHr);
        phase_pre<22, true>(Wu, WBs, tid);
        wgemmR(SLOTC(22), xf, w, c, g, aHz);
        float4 bir0 = *(const float4*)(wsb + 1152 + col00);
        float4 bir1 = *(const float4*)(wsb + 1152 + col01);
        float4 bhr0 = *(const float4*)(wsb + 1536 + col00);
        float4 bhr1 = *(const float4*)(wsb + 1536 + col01);
        phase_pre<23, true>(Wu, WBs, tid);
        loadX(xf, KPp, 1, c, g);
        wgemmR(SLOTC(23), xf, w, c, g, aHr);
        float4 biz0 = *(const float4*)(wsb + 1152 + 128 + col00);
        float4 biz1 = *(const float4*)(wsb + 1152 + 128 + col01);
        float4 bhz0 = *(const float4*)(wsb + 1536 + 128 + col00);
        float4 bhz1 = *(const float4*)(wsb + 1536 + 128 + col01);
        phase_pre<24, true>(Wu, WBs, tid);
        wgemmR(SLOTC(24), xf, w, c, g, aHz);

        #pragma unroll
        for (int i = 0; i < 2; i++){
            float4 bir = i ? bir1 : bir0; float4 bhr = i ? bhr1 : bhr0;
            float4 biz = i ? biz1 : biz0; float4 bhz = i ? bhz1 : bhz0;
            #pragma unroll
            for (int j = 0; j < 4; j++)
                #pragma unroll
                for (int r = 0; r < 4; r++){
                    rrA[i][j][r] = 1.f/(1.f + __expf(-(aIr[i][j][r] + (&bir.x)[r] + aHr[i][j][r] + (&bhr.x)[r])));
                    zzA[i][j][r] = 1.f/(1.f + __expf(-(aIz[i][j][r] + (&biz.x)[r] + aHz[i][j][r] + (&bhz.x)[r])));
                }
        }
    }
    {   // n gate + combine
        f32x4 aIn[2][4], aHn[2][4];
        phase_pre<25, true>(Wu, WBs, tid);
        zacc(aIn);
        loadX(xf, ACT, 0, c, g);
        wgemmR(SLOTC(25), xf, w, c, g, aIn);
        phase_pre<26, true>(Wu, WBs, tid);
        loadX(xf, ACT, 1, c, g);
        wgemmR(SLOTC(26), xf, w, c, g, aIn);
        phase_pre<27, true>(Wu, WBs, tid);
        zacc(aHn);
        loadX(xf, KPp, 0, c, g);
        wgemmR(SLOTC(27), xf, w, c, g, aHn);
        float4 bin0 = *(const float4*)(wsb + 1152 + 256 + col00);
        float4 bin1 = *(const float4*)(wsb + 1152 + 256 + col01);
        float4 bhn0 = *(const float4*)(wsb + 1536 + 256 + col00);
        float4 bhn1 = *(const float4*)(wsb + 1536 + 256 + col01);
        phase_pre<28, true>(Wu, WBs, tid);
        loadX(xf, KPp, 1, c, g);
        wgemmR(SLOTC(28), xf, w, c, g, aHn);

        #pragma unroll
        for (int i = 0; i < 2; i++){
            float4 bi = i ? bin1 : bin0; float4 bh = i ? bhn1 : bhn0;
            int col0 = w*32 + i*16 + g*4;
            int coff = swch(col0>>3, key)*8 + (col0&7);
            #pragma unroll
            for (int j = 0; j < 4; j++){
                int row = j*16 + c;
                uint2 hv = *(const uint2*)(KPp + row*128 + coff);
                float h0v[4] = { b2f((u16)(hv.x & 0xffffu)), b2f((u16)(hv.x >> 16)),
                                 b2f((u16)(hv.y & 0xffffu)), b2f((u16)(hv.y >> 16)) };
                f4v h3o;
                #pragma unroll
                for (int r = 0; r < 4; r++){
                    float xn = aIn[i][j][r] + (&bi.x)[r] + rrA[i][j][r]*(aHn[i][j][r] + (&bh.x)[r]);
                    float e2 = __expf(-2.f*fabsf(xn));
                    float th = (1.f - e2)/(1.f + e2);
                    th = (xn >= 0.f) ? th : -th;
                    float zv = zzA[i][j][r];
                    h3o[r] = (1.f - zv)*th + zv*h0v[r];
                }
                uint2 o; o.x = pk2(h3o[0],h3o[1]); o.y = pk2(h3o[2],h3o[3]);
                *(uint2*)(ACT + row*128 + coff) = o;   // h3 bf16 -> ACT (for qs GEMM)
                __builtin_nontemporal_store(h3o, (f4v*)(out_h3 + (rowbase + row)*128 + col0));
            }
        }
    }

    // ---- final linear (units 29,30) + qs stores ----
    {
        f32x4 qa[2][4];
        float4 lb0 = (col00 < 20) ? *(const float4*)(wsb + 1920 + col00) : (float4){0.f,0.f,0.f,0.f};
        float4 lb1 = (col01 < 20) ? *(const float4*)(wsb + 1920 + col01) : (float4){0.f,0.f,0.f,0.f};
        phase_pre<29, true>(Wu, WBs, tid);
        zacc(qa);
        loadX(xf, ACT, 0, c, g);
        wgemmR(SLOTC(29), xf, w, c, g, qa);
        phase_pre<30, false>(Wu, WBs, tid);
        loadX(xf, ACT, 1, c, g);
        wgemmR(SLOTC(30), xf, w, c, g, qa);

        #pragma unroll
        for (int i = 0; i < 2; i++){
            int col0 = w*32 + i*16 + g*4;
            if (col0 < 20){
                float4 lb = i ? lb1 : lb0;
                #pragma unroll
                for (int j = 0; j < 4; j++){
                    int row = j*16 + c;
                    f4v o;
                    o.x = qa[i][j][0]+lb.x; o.y = qa[i][j][1]+lb.y;
                    o.z = qa[i][j][2]+lb.z; o.w = qa[i][j][3]+lb.w;
                    __builtin_nontemporal_store(o, (f4v*)(out_qs + (rowbase + row)*20 + col0));
                }
            }
        }
    }
}

extern "C" void kernel_launch(void* const* d_in, const int* in_sizes, int n_in,
                              void* d_out, int out_size, void* d_ws, size_t ws_size,
                              hipStream_t stream) {
    const float* x     = (const float*)d_in[0];
    const int*   mask  = (const int*)  d_in[1];
    const float* h0    = (const float*)d_in[2];
    const float* enc_w = (const float*)d_in[3];
    const float* enc_b = (const float*)d_in[4];
    const float* q1_w  = (const float*)d_in[5];  const float* q1_b = (const float*)d_in[6];
    const float* k1_w  = (const float*)d_in[7];  const float* k1_b = (const float*)d_in[8];
    const float* v1_w  = (const float*)d_in[9];  const float* v1_b = (const float*)d_in[10];
    const float* o1_w  = (const float*)d_in[11]; const float* o1_b = (const float*)d_in[12];
    const float* q2_w  = (const float*)d_in[13]; const float* q2_b = (const float*)d_in[14];
    const float* k2_w  = (const float*)d_in[15]; const float* k2_b = (const float*)d_in[16];
    const float* v2_w  = (const float*)d_in[17]; const float* v2_b = (const float*)d_in[18];
    const float* o2_w  = (const float*)d_in[19]; const float* o2_b = (const float*)d_in[20];
    const float* gwih  = (const float*)d_in[21]; const float* gwhh = (const float*)d_in[22];
    const float* gbih  = (const float*)d_in[23]; const float* gbhh = (const float*)d_in[24];
    const float* lin_w = (const float*)d_in[25]; const float* lin_b = (const float*)d_in[26];

    const int bs = in_sizes[0] / (64 * 64);           // 4096
    float* out_qs = (float*)d_out;
    float* out_h3 = out_qs + (size_t)bs * 64 * 20;
    u16* W16 = (u16*)d_ws;

    const int total = NUNITS*8192 + NBIAS;
    hipLaunchKernelGGL(convert_weights, dim3((total + 255) / 256), dim3(256), 0, stream,
                       enc_w, q1_w, k1_w, v1_w, o1_w, q2_w, k2_w, v2_w, o2_w,
                       gwih, gwhh, lin_w,
                       enc_b, q1_b, k1_b, v1_b, o1_b, q2_b, k2_b, v2_b, o2_b,
                       gbih, gbhh, lin_b, W16);
    hipLaunchKernelGGL(drgn_pipe, dim3(bs), dim3(256), 0, stream,
                       x, mask, h0, W16, out_qs, out_h3);
}

// Round 7
// 328.821 us; speedup vs baseline: 1.7643x; 1.1122x over previous
//
#include <hip/hip_runtime.h>
#include <hip/hip_bf16.h>

typedef unsigned int u32;
typedef unsigned short u16;
typedef unsigned long long u64;

using bf16x8 = __attribute__((ext_vector_type(8))) short;
using f32x4  = __attribute__((ext_vector_type(4))) float;
typedef float f4v __attribute__((ext_vector_type(4)));

#define NUNITS 31
#define WS_BIAS_OFF (NUNITS*8192)
#define NBIAS 1952

__device__ __forceinline__ u32 pk2(float a, float b){
    __hip_bfloat162 h = __float22bfloat162_rn(make_float2(a, b));
    union { __hip_bfloat162 h2; u32 u; } cv; cv.h2 = h; return cv.u;
}
__device__ __forceinline__ float b2f(u16 v){ return __uint_as_float(((u32)v) << 16); }
__device__ __forceinline__ int swch(int chunk, int key){ return (chunk & ~7) | ((chunk ^ key) & 7); }

// ---------------- weight pre-conversion: per-(wave,lane) fragment order ----------------
// unit u layout: [w:4][t:4][lane:64][e:8] u16; t = i*2+kk (i = oc sub-tile, kk = k-32-block)
// element = W_logical[(w*2+i)*16 + (lane&15)][kh*64 + kk*32 + (lane>>4)*8 + e]
// unit order (same as R6): u0 enc | L0: q0,k0,v0,q1,k1,v1,o0,o1 (1..8) | L1: 9..16
// GRU 17..28: r_ih0,z_ih0,r_ih1,z_ih1, r_hh0,z_hh0,r_hh1,z_hh1, n_ih0,n_ih1,n_hh0,n_hh1
// u29,u30: lin kh0, kh1
__global__ __launch_bounds__(256) void convert_weights(
    const float* __restrict__ enc_w,
    const float* __restrict__ q1, const float* __restrict__ k1,
    const float* __restrict__ v1, const float* __restrict__ o1,
    const float* __restrict__ q2, const float* __restrict__ k2,
    const float* __restrict__ v2, const float* __restrict__ o2,
    const float* __restrict__ gih, const float* __restrict__ ghh,
    const float* __restrict__ lin,
    const float* __restrict__ enc_b,
    const float* __restrict__ q1b, const float* __restrict__ k1b,
    const float* __restrict__ v1b, const float* __restrict__ o1b,
    const float* __restrict__ q2b, const float* __restrict__ k2b,
    const float* __restrict__ v2b, const float* __restrict__ o2b,
    const float* __restrict__ gbih, const float* __restrict__ gbhh,
    const float* __restrict__ linb,
    u16* __restrict__ dst)
{
    int idx = blockIdx.x*256 + threadIdx.x;
    if (idx < NUNITS*8192){
        int u = idx >> 13, rem = idx & 8191;
        int w = rem >> 11;
        int t = (rem >> 9) & 3;
        int l = (rem >> 3) & 63;
        int e = idx & 7;
        int i = t >> 1, kk = t & 1;
        int oc = (w*2 + i)*16 + (l & 15);
        int kl = kk*32 + (l >> 4)*8 + e;
        float val;
        if (u == 0){
            val = enc_w[oc*64 + kl];
        } else if (u <= 16){
            int v = u - 1; int L = v >> 3; int r8 = v & 7;
            int mat, kh;
            if (r8 < 6){ mat = r8 % 3; kh = r8 / 3; } else { mat = 3; kh = r8 - 6; }
            const float* s;
            if (L == 0){ s = (mat==0)?q1:(mat==1)?k1:(mat==2)?v1:o1; }
            else       { s = (mat==0)?q2:(mat==1)?k2:(mat==2)?v2:o2; }
            val = s[oc*128 + kh*64 + kl];
        } else if (u <= 28){
            int v = u - 17;
            int gate, kh; const float* s;
            if (v < 8){ gate = v & 1; kh = (v >> 1) & 1; s = (v >= 4) ? ghh : gih; }
            else      { int w8 = v - 8; gate = 2; kh = w8 & 1; s = (w8 >= 2) ? ghh : gih; }
            val = s[(gate*128 + oc)*128 + kh*64 + kl];
        } else {
            int kh = u - 29;
            val = (oc < 20) ? lin[oc*128 + kh*64 + kl] : 0.f;
        }
        __hip_bfloat16 hv = __float2bfloat16(val);
        union { __hip_bfloat16 h; u16 us; } cv; cv.h = hv;
        dst[idx] = cv.us;
    } else if (idx < NUNITS*8192 + NBIAS){
        int i = idx - NUNITS*8192;
        float val;
        if      (i < 128)  val = enc_b[i];
        else if (i < 256)  val = q1b[i-128];
        else if (i < 384)  val = k1b[i-256];
        else if (i < 512)  val = v1b[i-384];
        else if (i < 640)  val = o1b[i-512];
        else if (i < 768)  val = q2b[i-640];
        else if (i < 896)  val = k2b[i-768];
        else if (i < 1024) val = v2b[i-896];
        else if (i < 1152) val = o2b[i-1024];
        else if (i < 1536) val = gbih[i-1152];
        else if (i < 1920) val = gbhh[i-1536];
        else if (i < 1940) val = linb[i-1920];
        else               val = 0.f;
        ((float*)(dst + NUNITS*8192))[i] = val;
    }
}

// ---------------- primitives ----------------
// lgkm-only barrier: never drains vmcnt (weight loads stay in flight)
#define BARX() do{ asm volatile("s_waitcnt lgkmcnt(0)" ::: "memory"); \
                   __builtin_amdgcn_s_barrier(); \
                   asm volatile("" ::: "memory"); }while(0)

struct WB { bf16x8 a[4]; };   // a[i*2+kk]

template<int U>
__device__ __forceinline__ WB load_unit(const u16* Wu, int w, int lane){
    const u16* p = Wu + U*8192 + w*2048 + lane*8;
    WB b;
    b.a[0] = *(const bf16x8*)(p);
    b.a[1] = *(const bf16x8*)(p + 512);
    b.a[2] = *(const bf16x8*)(p + 1024);
    b.a[3] = *(const bf16x8*)(p + 1536);
    return b;
}

template<int M,int N>
__device__ __forceinline__ void zacc(f32x4 (&a)[M][N]){
    #pragma unroll
    for (int i=0;i<M;i++)
        #pragma unroll
        for (int j=0;j<N;j++) a[i][j] = (f32x4){0.f,0.f,0.f,0.f};
}

// X fragments for one 64-k half: [tok-tile][kk], persisted in VGPRs across phases
struct XF { bf16x8 f[4][2]; };

__device__ __forceinline__ void loadX(XF& xf, const u16* X, int kh, int c, int g){
    const int key = c & 7;
    #pragma unroll
    for (int kk = 0; kk < 2; kk++){
        const int pw = (kk*4 + g) ^ key;
        #pragma unroll
        for (int j = 0; j < 4; j++)
            xf.f[j][kk] = *(const bf16x8*)(X + (j*16 + c)*128 + (kh*8 + pw)*8);
    }
}

// Y = X @ W^T : D[oc][tok]; W from registers
__device__ __forceinline__ void wgemmW(const WB& wb, const XF& xf, f32x4 (&acc)[2][4]){
    __builtin_amdgcn_s_setprio(1);
    #pragma unroll
    for (int kk = 0; kk < 2; kk++){
        #pragma unroll
        for (int j = 0; j < 4; j++){
            acc[0][j] = __builtin_amdgcn_mfma_f32_16x16x32_bf16(wb.a[kk],   xf.f[j][kk], acc[0][j], 0,0,0);
            acc[1][j] = __builtin_amdgcn_mfma_f32_16x16x32_bf16(wb.a[2+kk], xf.f[j][kk], acc[1][j], 0,0,0);
        }
    }
    __builtin_amdgcn_s_setprio(0);
}

// V-GEMM: D[token][vcol]; X frags are the A operand
__device__ __forceinline__ void vgemmW(const WB& wb, const XF& xf, f32x4 (&acc)[4][2]){
    __builtin_amdgcn_s_setprio(1);
    #pragma unroll
    for (int kk = 0; kk < 2; kk++){
        #pragma unroll
        for (int i = 0; i < 4; i++){
            acc[i][0] = __builtin_amdgcn_mfma_f32_16x16x32_bf16(xf.f[i][kk], wb.a[kk],   acc[i][0], 0,0,0);
            acc[i][1] = __builtin_amdgcn_mfma_f32_16x16x32_bf16(xf.f[i][kk], wb.a[2+kk], acc[i][1], 0,0,0);
        }
    }
    __builtin_amdgcn_s_setprio(0);
}

__device__ __forceinline__ void epiW(f32x4 (&acc)[2][4], float4 bv0, float4 bv1,
                                     u16* dst, int w, int c, int g){
    const int key = c & 7;
    #pragma unroll
    for (int i = 0; i < 2; i++){
        float4 bv = i ? bv1 : bv0;
        const int col0 = (w*2+i)*16 + g*4;
        const int coff = swch(col0>>3, key)*8 + (col0&7);
        #pragma unroll
        for (int j = 0; j < 4; j++){
            int row = j*16 + c;
            float v0 = fmaxf(acc[i][j][0]+bv.x, 0.f);
            float v1 = fmaxf(acc[i][j][1]+bv.y, 0.f);
            float v2 = fmaxf(acc[i][j][2]+bv.z, 0.f);
            float v3 = fmaxf(acc[i][j][3]+bv.w, 0.f);
            uint2 o; o.x = pk2(v0,v1); o.y = pk2(v2,v3);
            *(uint2*)(dst + row*128 + coff) = o;
        }
    }
}

// ---------------- one MHA layer ----------------
template<int LAYER>
__device__ __forceinline__ void mha_layer(const u16* Wu,
                                          u16* ACT, u16* QXp, u16* KPp,
                                          const float* wsb, const float* h0, size_t rowbase,
                                          int tid, int w, int lane, int c, int g, const u64* mbits)
{
    constexpr int UB = 1 + LAYER*8;     // q0 unit
    constexpr int BB = 128 + LAYER*512;
    const int key = c & 7;
    const int col00 = w*32 + g*4;
    const int col01 = col00 + 16;

    XF xf;
    f32x4 accQ[2][4], accK[2][4];
    f32x4 vacc[4][2];

    // entry: ACT holds layer input (barrier before call). b_q0/b_k0/b_v0 prefetched by caller.
    WB b_q0 = load_unit<UB+0>(Wu, w, lane);
    WB b_k0 = load_unit<UB+1>(Wu, w, lane);
    WB b_v0 = load_unit<UB+2>(Wu, w, lane);

    zacc(accQ); zacc(accK); zacc(vacc);
    loadX(xf, ACT, 0, c, g);
    wgemmW(b_q0, xf, accQ);
    WB b_q1 = load_unit<UB+3>(Wu, w, lane);
    wgemmW(b_k0, xf, accK);
    WB b_k1 = load_unit<UB+4>(Wu, w, lane);
    vgemmW(b_v0, xf, vacc);
    WB b_v1 = load_unit<UB+5>(Wu, w, lane);

    loadX(xf, ACT, 1, c, g);
    float4 bq0 = *(const float4*)(wsb + BB + col00);
    float4 bq1 = *(const float4*)(wsb + BB + col01);
    wgemmW(b_q1, xf, accQ);
    WB b_o0 = load_unit<UB+6>(Wu, w, lane);
    epiW(accQ, bq0, bq1, QXp, w, c, g);

    float4 bk0 = *(const float4*)(wsb + BB + 128 + col00);
    float4 bk1 = *(const float4*)(wsb + BB + 128 + col01);
    wgemmW(b_k1, xf, accK);
    WB b_o1 = load_unit<UB+7>(Wu, w, lane);
    epiW(accK, bk0, bk1, KPp, w, c, g);

    float bv0 = wsb[BB + 256 + w*32 + c];
    float bv1 = wsb[BB + 256 + w*32 + 16 + c];
    vgemmW(b_v1, xf, vacc);

    BARX();   // all waves' ACT reads + Q/K writes done -> safe to overwrite ACT with V^T

    // V^T epilogue -> ACT [128 vcol][64 tok] (wave-private rows w*32..w*32+31)
    #pragma unroll
    for (int j = 0; j < 2; j++){
        int vrow = w*32 + j*16 + c;
        float bv = j ? bv1 : bv0;
        #pragma unroll
        for (int i = 0; i < 4; i++){
            int kk = i >> 1, p = i & 1;
            float v0 = fmaxf(vacc[i][j][0]+bv, 0.f);
            float v1 = fmaxf(vacc[i][j][1]+bv, 0.f);
            float v2 = fmaxf(vacc[i][j][2]+bv, 0.f);
            float v3 = fmaxf(vacc[i][j][3]+bv, 0.f);
            uint2 o; o.x = pk2(v0,v1); o.y = pk2(v2,v3);
            *(uint2*)(ACT + vrow*64 + swch(kk*4+g, key)*8 + p*4) = o;
        }
    }

    // scores: mfma(K, Q) — wave-private columns (h = w)
    const int h = w;
    f32x4 sc[4][4];
    {
        bf16x8 kf[4];
        #pragma unroll
        for (int kt = 0; kt < 4; kt++)
            kf[kt] = *(const bf16x8*)(KPp + (kt*16 + c)*128 + swch(h*4+g, key)*8);
        __builtin_amdgcn_s_setprio(1);
        #pragma unroll
        for (int qt = 0; qt < 4; qt++){
            bf16x8 qf = *(const bf16x8*)(QXp + (qt*16 + c)*128 + swch(h*4+g, key)*8);
            #pragma unroll
            for (int kt = 0; kt < 4; kt++){
                f32x4 z4 = (f32x4){0.f,0.f,0.f,0.f};
                sc[qt][kt] = __builtin_amdgcn_mfma_f32_16x16x32_bf16(kf[kt], qf, z4, 0,0,0);
            }
        }
        __builtin_amdgcn_s_setprio(0);
    }

    // T14: issue h0 loads now (LAYER 1); latency hides under softmax+PV
    f4v hr[8];
    if (LAYER == 1){
        const float* hp = h0 + (rowbase + (tid>>2))*128 + (tid&3)*32;
        #pragma unroll
        for (int t = 0; t < 8; t++)
            hr[t] = __builtin_nontemporal_load((const f4v*)(hp + t*4));
    }

    {   // in-register masked softmax + PV (all wave-private)
        u32 pp[4][4][2];
        #pragma unroll
        for (int qt = 0; qt < 4; qt++){
            u64 mb = mbits[qt];
            float mx = -1e30f;
            #pragma unroll
            for (int kt = 0; kt < 4; kt++)
                #pragma unroll
                for (int r = 0; r < 4; r++){
                    float s = sc[qt][kt][r] * 0.17677669529663687f;
                    s = ((mb >> (kt*16 + g*4 + r)) & 1ull) ? s : -1e30f;
                    sc[qt][kt][r] = s;
                    mx = fmaxf(mx, s);
                }
            mx = fmaxf(mx, __shfl_xor(mx, 16));
            mx = fmaxf(mx, __shfl_xor(mx, 32));
            float sum = 0.f;
            #pragma unroll
            for (int kt = 0; kt < 4; kt++)
                #pragma unroll
                for (int r = 0; r < 4; r++){
                    float e = __expf(sc[qt][kt][r] - mx);
                    sc[qt][kt][r] = e; sum += e;
                }
            sum += __shfl_xor(sum, 16);
            sum += __shfl_xor(sum, 32);
            float inv = 1.f / sum;
            #pragma unroll
            for (int kt = 0; kt < 4; kt++){
                pp[qt][kt][0] = pk2(sc[qt][kt][0]*inv, sc[qt][kt][1]*inv);
                pp[qt][kt][1] = pk2(sc[qt][kt][2]*inv, sc[qt][kt][3]*inv);
            }
        }
        #pragma unroll
        for (int dt = 0; dt < 2; dt++){
            f32x4 pa[4];
            #pragma unroll
            for (int qt = 0; qt < 4; qt++) pa[qt] = (f32x4){0.f,0.f,0.f,0.f};
            #pragma unroll
            for (int kk = 0; kk < 2; kk++){
                bf16x8 vt = *(const bf16x8*)(ACT + (h*32 + dt*16 + c)*64 + ((kk*4+g)^key)*8);
                __builtin_amdgcn_s_setprio(1);
                #pragma unroll
                for (int qt = 0; qt < 4; qt++){
                    union { u32 u4[4]; bf16x8 v8; } bbv;
                    bbv.u4[0]=pp[qt][kk*2][0];   bbv.u4[1]=pp[qt][kk*2][1];
                    bbv.u4[2]=pp[qt][kk*2+1][0]; bbv.u4[3]=pp[qt][kk*2+1][1];
                    pa[qt] = __builtin_amdgcn_mfma_f32_16x16x32_bf16(vt, bbv.v8, pa[qt], 0,0,0);
                }
                __builtin_amdgcn_s_setprio(0);
            }
            #pragma unroll
            for (int qt = 0; qt < 4; qt++){
                int col = h*32 + dt*16 + g*4;
                uint2 o; o.x = pk2(pa[qt][0], pa[qt][1]); o.y = pk2(pa[qt][2], pa[qt][3]);
                *(uint2*)(QXp + (qt*16 + c)*128 + swch(col>>3, key)*8 + (col&7)) = o;
            }
        }
    }

    BARX();   // PV writes visible; all scores/PV reads done (KPp, ACT free)

    // T14 write-late: h0 bf16 -> KPp (safe: all scores reads done)
    if (LAYER == 1){
        int hrow = tid >> 2, seg = tid & 3;
        #pragma unroll
        for (int cc = 0; cc < 4; cc++){
            int p = seg*4 + cc;
            int ps = (p & 8) | ((p ^ (hrow & 7)) & 7);
            f4v fa = hr[cc*2], fb = hr[cc*2+1];
            uint4 o; o.x = pk2(fa.x,fa.y); o.y = pk2(fa.z,fa.w);
            o.z = pk2(fb.x,fb.y); o.w = pk2(fb.z,fb.w);
            *(uint4*)(KPp + hrow*128 + ps*8) = o;
        }
    }

    // O-projection: ACT = relu(X1 @ Wo^T + b); prefetch next section's first 2 units
    f32x4 acc[2][4];
    zacc(acc);
    loadX(xf, QXp, 0, c, g);
    wgemmW(b_o0, xf, acc);
    WB b_n0 = load_unit<UB+8>(Wu, w, lane);    // next layer q0 / GRU r_ih0
    loadX(xf, QXp, 1, c, g);
    float4 bo0 = *(const float4*)(wsb + BB + 384 + col00);
    float4 bo1 = *(const float4*)(wsb + BB + 384 + col01);
    wgemmW(b_o1, xf, acc);
    WB b_n1 = load_unit<UB+9>(Wu, w, lane);
    epiW(acc, bo0, bo1, ACT, w, c, g);
    // keep prefetched regs alive without consuming (they reload cheaply in next section from L1/L2)
    asm volatile("" :: "v"(b_n0.a[0]), "v"(b_n1.a[0]));

    BARX();   // ACT (new layer input / h2) visible
}

// ---------------- main fused kernel: 1 batch item / block, 256 threads ----------------
__global__ __launch_bounds__(256, 2) void drgn_pipe(
    const float* __restrict__ x, const int* __restrict__ maskg,
    const float* __restrict__ h0, const u16* __restrict__ W16,
    float* __restrict__ out_qs, float* __restrict__ out_h3)
{
    __shared__ __align__(16) u16 SMEM[24576];   // 49152 B: 3 x [64][128] bf16
    u16* ACT = SMEM;                 // layer act / V^T / h2 / h3
    u16* QXp = SMEM + 8192;          // x-in / Q / X1
    u16* KPp = SMEM + 16384;         // K / h0-bf16 (transient: mask u64[64])

    const int tid = threadIdx.x;
    const int w = tid >> 6, lane = tid & 63;
    const int c = lane & 15, g = lane >> 4;
    const int key = c & 7;
    const size_t rowbase = (size_t)blockIdx.x * 64;
    const u16* Wu = W16;
    const float* wsb = (const float*)(W16 + WS_BIAS_OFF);
    const int col00 = w*32 + g*4;
    const int col01 = col00 + 16;

    // ---- prologue: mask bits -> regs (via KPp transient), x -> QXp bf16 ----
    u64* MrowT = (u64*)KPp;
    #pragma unroll 4
    for (int rr = 0; rr < 16; rr++){
        int row = w*16 + rr;
        int mv = __builtin_nontemporal_load(maskg + (rowbase + row)*64 + lane);
        u64 bits = __ballot(mv != 0);
        if (lane == 0) MrowT[row] = bits;
    }
    for (int i = tid; i < 512; i += 256){
        int row = i >> 3, p = i & 7;
        int lc = (p ^ (row & 7)) & 7;
        const float* sp = x + (rowbase + row)*64 + lc*8;
        f4v f0 = __builtin_nontemporal_load((const f4v*)sp);
        f4v f1 = __builtin_nontemporal_load((const f4v*)(sp + 4));
        uint4 o; o.x = pk2(f0.x,f0.y); o.y = pk2(f0.z,f0.w);
        o.z = pk2(f1.x,f1.y); o.w = pk2(f1.z,f1.w);
        *(uint4*)(QXp + row*128 + p*8) = o;
    }
    WB b_enc = load_unit<0>(Wu, w, lane);
    __syncthreads();
    u64 mbits[4];
    #pragma unroll
    for (int qt = 0; qt < 4; qt++) mbits[qt] = MrowT[qt*16 + c];

    // ---- encoder (unit 0): ACT = relu(x @ enc^T + b) ----
    {
        XF xf;
        f32x4 acc[2][4];
        float4 b0 = *(const float4*)(wsb + col00);
        float4 b1 = *(const float4*)(wsb + col01);
        zacc(acc);
        loadX(xf, QXp, 0, c, g);
        wgemmW(b_enc, xf, acc);
        epiW(acc, b0, b1, ACT, w, c, g);
    }
    BARX();   // ACT ready

    // ---- two MHA layers ----
    mha_layer<0>(Wu, ACT, QXp, KPp, wsb, h0, rowbase, tid, w, lane, c, g, mbits);
    mha_layer<1>(Wu, ACT, QXp, KPp, wsb, h0, rowbase, tid, w, lane, c, g, mbits);

    // ---- GRU: ACT = h2, KPp = h0(bf16) ----
    XF xf;
    float rrA[2][4][4], zzA[2][4][4];
    {
        f32x4 aIr[2][4], aIz[2][4], aHr[2][4], aHz[2][4];
        WB g17 = load_unit<17>(Wu, w, lane);
        WB g18 = load_unit<18>(Wu, w, lane);
        zacc(aIr); zacc(aIz);
        loadX(xf, ACT, 0, c, g);
        wgemmW(g17, xf, aIr);
        WB g19 = load_unit<19>(Wu, w, lane);
        wgemmW(g18, xf, aIz);
        WB g20 = load_unit<20>(Wu, w, lane);
        loadX(xf, ACT, 1, c, g);
        wgemmW(g19, xf, aIr);
        WB g21 = load_unit<21>(Wu, w, lane);
        wgemmW(g20, xf, aIz);
        WB g22 = load_unit<22>(Wu, w, lane);
        zacc(aHr); zacc(aHz);
        loadX(xf, KPp, 0, c, g);
        wgemmW(g21, xf, aHr);
        WB g23 = load_unit<23>(Wu, w, lane);
        wgemmW(g22, xf, aHz);
        WB g24 = load_unit<24>(Wu, w, lane);
        loadX(xf, KPp, 1, c, g);
        wgemmW(g23, xf, aHr);
        wgemmW(g24, xf, aHz);

        float4 bir0 = *(const float4*)(wsb + 1152 + col00);
        float4 bir1 = *(const float4*)(wsb + 1152 + col01);
        float4 bhr0 = *(const float4*)(wsb + 1536 + col00);
        float4 bhr1 = *(const float4*)(wsb + 1536 + col01);
        float4 biz0 = *(const float4*)(wsb + 1152 + 128 + col00);
        float4 biz1 = *(const float4*)(wsb + 1152 + 128 + col01);
        float4 bhz0 = *(const float4*)(wsb + 1536 + 128 + col00);
        float4 bhz1 = *(const float4*)(wsb + 1536 + 128 + col01);
        #pragma unroll
        for (int i = 0; i < 2; i++){
            float4 bir = i ? bir1 : bir0; float4 bhr = i ? bhr1 : bhr0;
            float4 biz = i ? biz1 : biz0; float4 bhz = i ? bhz1 : bhz0;
            #pragma unroll
            for (int j = 0; j < 4; j++)
                #pragma unroll
                for (int r = 0; r < 4; r++){
                    rrA[i][j][r] = 1.f/(1.f + __expf(-(aIr[i][j][r] + (&bir.x)[r] + aHr[i][j][r] + (&bhr.x)[r])));
                    zzA[i][j][r] = 1.f/(1.f + __expf(-(aIz[i][j][r] + (&biz.x)[r] + aHz[i][j][r] + (&bhz.x)[r])));
                }
        }
    }
    WB g29, g30;
    {   // n gate + combine
        f32x4 aIn[2][4], aHn[2][4];
        WB g25 = load_unit<25>(Wu, w, lane);
        WB g26 = load_unit<26>(Wu, w, lane);
        zacc(aIn);
        loadX(xf, ACT, 0, c, g);
        wgemmW(g25, xf, aIn);
        WB g27 = load_unit<27>(Wu, w, lane);
        loadX(xf, ACT, 1, c, g);
        wgemmW(g26, xf, aIn);
        WB g28 = load_unit<28>(Wu, w, lane);
        zacc(aHn);
        loadX(xf, KPp, 0, c, g);
        wgemmW(g27, xf, aHn);
        g29 = load_unit<29>(Wu, w, lane);
        loadX(xf, KPp, 1, c, g);
        wgemmW(g28, xf, aHn);
        g30 = load_unit<30>(Wu, w, lane);

        float4 bin0 = *(const float4*)(wsb + 1152 + 256 + col00);
        float4 bin1 = *(const float4*)(wsb + 1152 + 256 + col01);
        float4 bhn0 = *(const float4*)(wsb + 1536 + 256 + col00);
        float4 bhn1 = *(const float4*)(wsb + 1536 + 256 + col01);

        BARX();   // all waves' ACT/KPp reads done -> h3 may overwrite ACT

        #pragma unroll
        for (int i = 0; i < 2; i++){
            float4 bi = i ? bin1 : bin0; float4 bh = i ? bhn1 : bhn0;
            int col0 = w*32 + i*16 + g*4;
            int coff = swch(col0>>3, key)*8 + (col0&7);
            #pragma unroll
            for (int j = 0; j < 4; j++){
                int row = j*16 + c;
                uint2 hv = *(const uint2*)(KPp + row*128 + coff);
                float h0v[4] = { b2f((u16)(hv.x & 0xffffu)), b2f((u16)(hv.x >> 16)),
                                 b2f((u16)(hv.y & 0xffffu)), b2f((u16)(hv.y >> 16)) };
                f4v h3o;
                #pragma unroll
                for (int r = 0; r < 4; r++){
                    float xn = aIn[i][j][r] + (&bi.x)[r] + rrA[i][j][r]*(aHn[i][j][r] + (&bh.x)[r]);
                    float e2 = __expf(-2.f*fabsf(xn));
                    float th = (1.f - e2)/(1.f + e2);
                    th = (xn >= 0.f) ? th : -th;
                    float zv = zzA[i][j][r];
                    h3o[r] = (1.f - zv)*th + zv*h0v[r];
                }
                uint2 o; o.x = pk2(h3o[0],h3o[1]); o.y = pk2(h3o[2],h3o[3]);
                *(uint2*)(ACT + row*128 + coff) = o;   // h3 bf16 -> ACT (for qs GEMM)
                __builtin_nontemporal_store(h3o, (f4v*)(out_h3 + (rowbase + row)*128 + col0));
            }
        }
    }
    BARX();   // h3 visible

    // ---- final linear (units 29,30) + qs stores ----
    {
        f32x4 qa[2][4];
        float4 lb0 = (col00 < 20) ? *(const float4*)(wsb + 1920 + col00) : (float4){0.f,0.f,0.f,0.f};
        float4 lb1 = (col01 < 20) ? *(const float4*)(wsb + 1920 + col01) : (float4){0.f,0.f,0.f,0.f};
        zacc(qa);
        loadX(xf, ACT, 0, c, g);
        wgemmW(g29, xf, qa);
        loadX(xf, ACT, 1, c, g);
        wgemmW(g30, xf, qa);

        #pragma unroll
        for (int i = 0; i < 2; i++){
            int col0 = w*32 + i*16 + g*4;
            if (col0 < 20){
                float4 lb = i ? lb1 : lb0;
                #pragma unroll
                for (int j = 0; j < 4; j++){
                    int row = j*16 + c;
                    f4v o;
                    o.x = qa[i][j][0]+lb.x; o.y = qa[i][j][1]+lb.y;
                    o.z = qa[i][j][2]+lb.z; o.w = qa[i][j][3]+lb.w;
                    __builtin_nontemporal_store(o, (f4v*)(out_qs + (rowbase + row)*20 + col0));
                }
            }
        }
    }
}

extern "C" void kernel_launch(void* const* d_in, const int* in_sizes, int n_in,
                              void* d_out, int out_size, void* d_ws, size_t ws_size,
                              hipStream_t stream) {
    const float* x     = (const float*)d_in[0];
    const int*   mask  = (const int*)  d_in[1];
    const float* h0    = (const float*)d_in[2];
    const float* enc_w = (const float*)d_in[3];
    const float* enc_b = (const float*)d_in[4];
    const float* q1_w  = (const float*)d_in[5];  const float* q1_b = (const float*)d_in[6];
    const float* k1_w  = (const float*)d_in[7];  const float* k1_b = (const float*)d_in[8];
    const float* v1_w  = (const float*)d_in[9];  const float* v1_b = (const float*)d_in[10];
    const float* o1_w  = (const float*)d_in[11]; const float* o1_b = (const float*)d_in[12];
    const float* q2_w  = (const float*)d_in[13]; const float* q2_b = (const float*)d_in[14];
    const float* k2_w  = (const float*)d_in[15]; const float* k2_b = (const float*)d_in[16];
    const float* v2_w  = (const float*)d_in[17]; const float* v2_b = (const float*)d_in[18];
    const float* o2_w  = (const float*)d_in[19]; const float* o2_b = (const float*)d_in[20];
    const float* gwih  = (const float*)d_in[21]; const float* gwhh = (const float*)d_in[22];
    const float* gbih  = (const float*)d_in[23]; const float* gbhh = (const float*)d_in[24];
    const float* lin_w = (const float*)d_in[25]; const float* lin_b = (const float*)d_in[26];

    const int bs = in_sizes[0] / (64 * 64);           // 4096
    float* out_qs = (float*)d_out;
    float* out_h3 = out_qs + (size_t)bs * 64 * 20;
    u16* W16 = (u16*)d_ws;

    const int total = NUNITS*8192 + NBIAS;
    hipLaunchKernelGGL(convert_weights, dim3((total + 255) / 256), dim3(256), 0, stream,
                       enc_w, q1_w, k1_w, v1_w, o1_w, q2_w, k2_w, v2_w, o2_w,
                       gwih, gwhh, lin_w,
                       enc_b, q1_b, k1_b, v1_b, o1_b, q2_b, k2_b, v2_b, o2_b,
                       gbih, gbhh, lin_b, W16);
    hipLaunchKernelGGL(drgn_pipe, dim3(bs), dim3(256), 0, stream,
                       x, mask, h0, W16, out_qs, out_h3);
}

// Round 8
// 313.060 us; speedup vs baseline: 1.8531x; 1.0503x over previous
//
#include <hip/hip_runtime.h>
#include <hip/hip_bf16.h>

typedef unsigned int u32;
typedef unsigned short u16;
typedef unsigned long long u64;

using bf16x8 = __attribute__((ext_vector_type(8))) short;
using f32x4  = __attribute__((ext_vector_type(4))) float;
typedef float f4v __attribute__((ext_vector_type(4)));

#define NUNITS 31
#define WS_BIAS_OFF (NUNITS*8192)
#define NBIAS 1952
#define SCL2 0.25503512f     // 1/sqrt(32) * log2(e)
#define L2E  1.4426950408889634f

__device__ __forceinline__ u32 pk2(float a, float b){
    __hip_bfloat162 h = __float22bfloat162_rn(make_float2(a, b));
    union { __hip_bfloat162 h2; u32 u; } cv; cv.h2 = h; return cv.u;
}
__device__ __forceinline__ float b2f(u16 v){ return __uint_as_float(((u32)v) << 16); }
__device__ __forceinline__ int swch(int chunk, int key){ return (chunk & ~7) | ((chunk ^ key) & 7); }
__device__ __forceinline__ float sigx(float v){
    return __builtin_amdgcn_rcpf(1.f + __builtin_amdgcn_exp2f(-L2E * v));
}

// ---------------- weight pre-conversion (identical layout to R7) ----------------
__global__ __launch_bounds__(256) void convert_weights(
    const float* __restrict__ enc_w,
    const float* __restrict__ q1, const float* __restrict__ k1,
    const float* __restrict__ v1, const float* __restrict__ o1,
    const float* __restrict__ q2, const float* __restrict__ k2,
    const float* __restrict__ v2, const float* __restrict__ o2,
    const float* __restrict__ gih, const float* __restrict__ ghh,
    const float* __restrict__ lin,
    const float* __restrict__ enc_b,
    const float* __restrict__ q1b, const float* __restrict__ k1b,
    const float* __restrict__ v1b, const float* __restrict__ o1b,
    const float* __restrict__ q2b, const float* __restrict__ k2b,
    const float* __restrict__ v2b, const float* __restrict__ o2b,
    const float* __restrict__ gbih, const float* __restrict__ gbhh,
    const float* __restrict__ linb,
    u16* __restrict__ dst)
{
    int idx = blockIdx.x*256 + threadIdx.x;
    if (idx < NUNITS*8192){
        int u = idx >> 13, rem = idx & 8191;
        int w = rem >> 11;
        int t = (rem >> 9) & 3;
        int l = (rem >> 3) & 63;
        int e = idx & 7;
        int i = t >> 1, kk = t & 1;
        int oc = (w*2 + i)*16 + (l & 15);
        int kl = kk*32 + (l >> 4)*8 + e;
        float val;
        if (u == 0){
            val = enc_w[oc*64 + kl];
        } else if (u <= 16){
            int v = u - 1; int L = v >> 3; int r8 = v & 7;
            int mat, kh;
            if (r8 < 6){ mat = r8 % 3; kh = r8 / 3; } else { mat = 3; kh = r8 - 6; }
            const float* s;
            if (L == 0){ s = (mat==0)?q1:(mat==1)?k1:(mat==2)?v1:o1; }
            else       { s = (mat==0)?q2:(mat==1)?k2:(mat==2)?v2:o2; }
            val = s[oc*128 + kh*64 + kl];
        } else if (u <= 28){
            int v = u - 17;
            int gate, kh; const float* s;
            if (v < 8){ gate = v & 1; kh = (v >> 1) & 1; s = (v >= 4) ? ghh : gih; }
            else      { int w8 = v - 8; gate = 2; kh = w8 & 1; s = (w8 >= 2) ? ghh : gih; }
            val = s[(gate*128 + oc)*128 + kh*64 + kl];
        } else {
            int kh = u - 29;
            val = (oc < 20) ? lin[oc*128 + kh*64 + kl] : 0.f;
        }
        __hip_bfloat16 hv = __float2bfloat16(val);
        union { __hip_bfloat16 h; u16 us; } cv; cv.h = hv;
        dst[idx] = cv.us;
    } else if (idx < NUNITS*8192 + NBIAS){
        int i = idx - NUNITS*8192;
        float val;
        if      (i < 128)  val = enc_b[i];
        else if (i < 256)  val = q1b[i-128];
        else if (i < 384)  val = k1b[i-256];
        else if (i < 512)  val = v1b[i-384];
        else if (i < 640)  val = o1b[i-512];
        else if (i < 768)  val = q2b[i-640];
        else if (i < 896)  val = k2b[i-768];
        else if (i < 1024) val = v2b[i-896];
        else if (i < 1152) val = o2b[i-1024];
        else if (i < 1536) val = gbih[i-1152];
        else if (i < 1920) val = gbhh[i-1536];
        else if (i < 1940) val = linb[i-1920];
        else               val = 0.f;
        ((float*)(dst + NUNITS*8192))[i] = val;
    }
}

// ---------------- primitives ----------------
#define BARX() do{ asm volatile("s_waitcnt lgkmcnt(0)" ::: "memory"); \
                   __builtin_amdgcn_s_barrier(); \
                   asm volatile("" ::: "memory"); }while(0)

struct WB { bf16x8 a[4]; };   // a[i*2+kk]

template<int U>
__device__ __forceinline__ WB load_unit(const u16* Wu, int w, int lane){
    const u16* p = Wu + U*8192 + w*2048 + lane*8;
    WB b;
    b.a[0] = *(const bf16x8*)(p);
    b.a[1] = *(const bf16x8*)(p + 512);
    b.a[2] = *(const bf16x8*)(p + 1024);
    b.a[3] = *(const bf16x8*)(p + 1536);
    return b;
}

#define Z4 ((f32x4){0.f,0.f,0.f,0.f})
#define MFMA(a,b,c) __builtin_amdgcn_mfma_f32_16x16x32_bf16((a),(b),(c),0,0,0)

// X fragments for one 64-k half
struct XF { bf16x8 f[4][2]; };

__device__ __forceinline__ void loadX(XF& xf, const u16* X, int kh, int c, int g){
    const int key = c & 7;
    #pragma unroll
    for (int kk = 0; kk < 2; kk++){
        const int pw = (kk*4 + g) ^ key;
        #pragma unroll
        for (int j = 0; j < 4; j++)
            xf.f[j][kk] = *(const bf16x8*)(X + (j*16 + c)*128 + (kh*8 + pw)*8);
    }
}

// Y = X @ W^T : D[oc][tok]; FIRST = start accumulation from zero constant
template<bool FIRST>
__device__ __forceinline__ void wgemmW(const WB& wb, const XF& xf, f32x4 (&acc)[2][4]){
    __builtin_amdgcn_s_setprio(1);
    #pragma unroll
    for (int j = 0; j < 4; j++){
        acc[0][j] = FIRST ? MFMA(wb.a[0], xf.f[j][0], Z4) : MFMA(wb.a[0], xf.f[j][0], acc[0][j]);
        acc[1][j] = FIRST ? MFMA(wb.a[2], xf.f[j][0], Z4) : MFMA(wb.a[2], xf.f[j][0], acc[1][j]);
    }
    #pragma unroll
    for (int j = 0; j < 4; j++){
        acc[0][j] = MFMA(wb.a[1], xf.f[j][1], acc[0][j]);
        acc[1][j] = MFMA(wb.a[3], xf.f[j][1], acc[1][j]);
    }
    __builtin_amdgcn_s_setprio(0);
}

// V-GEMM: D[token][vcol]
template<bool FIRST>
__device__ __forceinline__ void vgemmW(const WB& wb, const XF& xf, f32x4 (&acc)[4][2]){
    __builtin_amdgcn_s_setprio(1);
    #pragma unroll
    for (int i = 0; i < 4; i++){
        acc[i][0] = FIRST ? MFMA(xf.f[i][0], wb.a[0], Z4) : MFMA(xf.f[i][0], wb.a[0], acc[i][0]);
        acc[i][1] = FIRST ? MFMA(xf.f[i][0], wb.a[2], Z4) : MFMA(xf.f[i][0], wb.a[2], acc[i][1]);
    }
    #pragma unroll
    for (int i = 0; i < 4; i++){
        acc[i][0] = MFMA(xf.f[i][1], wb.a[1], acc[i][0]);
        acc[i][1] = MFMA(xf.f[i][1], wb.a[3], acc[i][1]);
    }
    __builtin_amdgcn_s_setprio(0);
}

// QS: fold softmax scale (exp2 domain) into Q store
template<bool QS>
__device__ __forceinline__ void epiW(f32x4 (&acc)[2][4], float4 bv0, float4 bv1,
                                     u16* dst, int w, int c, int g){
    const int key = c & 7;
    #pragma unroll
    for (int i = 0; i < 2; i++){
        float4 bv = i ? bv1 : bv0;
        const int col0 = (w*2+i)*16 + g*4;
        const int coff = swch(col0>>3, key)*8 + (col0&7);
        #pragma unroll
        for (int j = 0; j < 4; j++){
            int row = j*16 + c;
            float v0 = fmaxf(acc[i][j][0]+bv.x, 0.f);
            float v1 = fmaxf(acc[i][j][1]+bv.y, 0.f);
            float v2 = fmaxf(acc[i][j][2]+bv.z, 0.f);
            float v3 = fmaxf(acc[i][j][3]+bv.w, 0.f);
            if (QS){ v0 *= SCL2; v1 *= SCL2; v2 *= SCL2; v3 *= SCL2; }
            uint2 o; o.x = pk2(v0,v1); o.y = pk2(v2,v3);
            *(uint2*)(dst + row*128 + coff) = o;
        }
    }
}

// ---------------- one MHA layer; consumes preloaded q0/k0/v0, returns next section's ----------------
template<int LAYER>
__device__ __forceinline__ void mha_layer(const u16* Wu,
                                          u16* ACT, u16* QXp, u16* KPp,
                                          const float* wsb, const float* h0, size_t rowbase,
                                          int tid, int w, int lane, int c, int g, const u64* mbits,
                                          WB b_q0, WB b_k0, WB b_v0,
                                          WB& nx0, WB& nx1, WB& nx2)
{
    constexpr int UB = 1 + LAYER*8;
    constexpr int BB = 128 + LAYER*512;
    const int key = c & 7;
    const int col00 = w*32 + g*4;
    const int col01 = col00 + 16;

    XF xf;
    f32x4 accQ[2][4], accK[2][4];
    f32x4 vacc[4][2];

    loadX(xf, ACT, 0, c, g);
    wgemmW<true>(b_q0, xf, accQ);
    WB b_q1 = load_unit<UB+3>(Wu, w, lane);
    wgemmW<true>(b_k0, xf, accK);
    WB b_k1 = load_unit<UB+4>(Wu, w, lane);
    vgemmW<true>(b_v0, xf, vacc);
    WB b_v1 = load_unit<UB+5>(Wu, w, lane);

    loadX(xf, ACT, 1, c, g);
    float4 bq0 = *(const float4*)(wsb + BB + col00);
    float4 bq1 = *(const float4*)(wsb + BB + col01);
    wgemmW<false>(b_q1, xf, accQ);
    WB b_o0 = load_unit<UB+6>(Wu, w, lane);
    epiW<true>(accQ, bq0, bq1, QXp, w, c, g);     // Q pre-scaled into exp2 domain

    float4 bk0 = *(const float4*)(wsb + BB + 128 + col00);
    float4 bk1 = *(const float4*)(wsb + BB + 128 + col01);
    wgemmW<false>(b_k1, xf, accK);
    WB b_o1 = load_unit<UB+7>(Wu, w, lane);
    epiW<false>(accK, bk0, bk1, KPp, w, c, g);

    float bv0 = wsb[BB + 256 + w*32 + c];
    float bv1 = wsb[BB + 256 + w*32 + 16 + c];
    vgemmW<false>(b_v1, xf, vacc);

    BARX();   // all waves' ACT reads + Q/K writes done -> safe to overwrite ACT with V^T

    // V^T epilogue -> ACT [128 vcol][64 tok] (wave-private rows)
    #pragma unroll
    for (int j = 0; j < 2; j++){
        int vrow = w*32 + j*16 + c;
        float bv = j ? bv1 : bv0;
        #pragma unroll
        for (int i = 0; i < 4; i++){
            int kk = i >> 1, p = i & 1;
            float v0 = fmaxf(vacc[i][j][0]+bv, 0.f);
            float v1 = fmaxf(vacc[i][j][1]+bv, 0.f);
            float v2 = fmaxf(vacc[i][j][2]+bv, 0.f);
            float v3 = fmaxf(vacc[i][j][3]+bv, 0.f);
            uint2 o; o.x = pk2(v0,v1); o.y = pk2(v2,v3);
            *(uint2*)(ACT + vrow*64 + swch(kk*4+g, key)*8 + p*4) = o;
        }
    }

    // scores: mfma(K, Qs) — wave-private (h = w); result already in exp2 domain
    const int h = w;
    f32x4 sc[4][4];
    {
        bf16x8 kf[4];
        #pragma unroll
        for (int kt = 0; kt < 4; kt++)
            kf[kt] = *(const bf16x8*)(KPp + (kt*16 + c)*128 + swch(h*4+g, key)*8);
        __builtin_amdgcn_s_setprio(1);
        #pragma unroll
        for (int qt = 0; qt < 4; qt++){
            bf16x8 qf = *(const bf16x8*)(QXp + (qt*16 + c)*128 + swch(h*4+g, key)*8);
            #pragma unroll
            for (int kt = 0; kt < 4; kt++)
                sc[qt][kt] = MFMA(kf[kt], qf, Z4);
        }
        __builtin_amdgcn_s_setprio(0);
    }

    // T14: issue h0 loads now (LAYER 1); latency hides under softmax+PV
    f4v hr[8];
    if (LAYER == 1){
        const float* hp = h0 + (rowbase + (tid>>2))*128 + (tid&3)*32;
        #pragma unroll
        for (int t = 0; t < 8; t++)
            hr[t] = __builtin_nontemporal_load((const f4v*)(hp + t*4));
    }

    {   // no-max exp2 softmax (unnormalized P) + PV + post-normalization
        u32 pp[4][4][2];
        float inv[4];
        #pragma unroll
        for (int qt = 0; qt < 4; qt++){
            u64 mb = mbits[qt];
            float sum = 0.f;
            #pragma unroll
            for (int kt = 0; kt < 4; kt++)
                #pragma unroll
                for (int r = 0; r < 4; r++){
                    float s = ((mb >> (kt*16 + g*4 + r)) & 1ull) ? sc[qt][kt][r] : -1e30f;
                    float e = __builtin_amdgcn_exp2f(s);
                    sc[qt][kt][r] = e; sum += e;
                }
            sum += __shfl_xor(sum, 16);
            sum += __shfl_xor(sum, 32);
            inv[qt] = __builtin_amdgcn_rcpf(sum);
            #pragma unroll
            for (int kt = 0; kt < 4; kt++){
                pp[qt][kt][0] = pk2(sc[qt][kt][0], sc[qt][kt][1]);
                pp[qt][kt][1] = pk2(sc[qt][kt][2], sc[qt][kt][3]);
            }
        }
        #pragma unroll
        for (int dt = 0; dt < 2; dt++){
            f32x4 pa[4];
            #pragma unroll
            for (int kk = 0; kk < 2; kk++){
                bf16x8 vt = *(const bf16x8*)(ACT + (h*32 + dt*16 + c)*64 + ((kk*4+g)^key)*8);
                __builtin_amdgcn_s_setprio(1);
                #pragma unroll
                for (int qt = 0; qt < 4; qt++){
                    union { u32 u4[4]; bf16x8 v8; } bbv;
                    bbv.u4[0]=pp[qt][kk*2][0];   bbv.u4[1]=pp[qt][kk*2][1];
                    bbv.u4[2]=pp[qt][kk*2+1][0]; bbv.u4[3]=pp[qt][kk*2+1][1];
                    pa[qt] = (kk == 0) ? MFMA(vt, bbv.v8, Z4) : MFMA(vt, bbv.v8, pa[qt]);
                }
                __builtin_amdgcn_s_setprio(0);
            }
            #pragma unroll
            for (int qt = 0; qt < 4; qt++){
                int col = h*32 + dt*16 + g*4;
                float iv = inv[qt];
                uint2 o; o.x = pk2(pa[qt][0]*iv, pa[qt][1]*iv); o.y = pk2(pa[qt][2]*iv, pa[qt][3]*iv);
                *(uint2*)(QXp + (qt*16 + c)*128 + swch(col>>3, key)*8 + (col&7)) = o;
            }
        }
    }

    BARX();   // PV writes visible; scores/PV reads done (KPp, ACT free)

    // T14 write-late: h0 bf16 -> KPp
    if (LAYER == 1){
        int hrow = tid >> 2, seg = tid & 3;
        #pragma unroll
        for (int cc = 0; cc < 4; cc++){
            int p = seg*4 + cc;
            int ps = (p & 8) | ((p ^ (hrow & 7)) & 7);
            f4v fa = hr[cc*2], fb = hr[cc*2+1];
            uint4 o; o.x = pk2(fa.x,fa.y); o.y = pk2(fa.z,fa.w);
            o.z = pk2(fb.x,fb.y); o.w = pk2(fb.z,fb.w);
            *(uint4*)(KPp + hrow*128 + ps*8) = o;
        }
    }

    // O-projection; prefetch next section's first 3 units (USED by caller)
    f32x4 acc[2][4];
    loadX(xf, QXp, 0, c, g);
    wgemmW<true>(b_o0, xf, acc);
    nx0 = load_unit<UB+8>(Wu, w, lane);
    nx1 = load_unit<UB+9>(Wu, w, lane);
    loadX(xf, QXp, 1, c, g);
    float4 bo0 = *(const float4*)(wsb + BB + 384 + col00);
    float4 bo1 = *(const float4*)(wsb + BB + 384 + col01);
    wgemmW<false>(b_o1, xf, acc);
    nx2 = load_unit<UB+10>(Wu, w, lane);
    epiW<false>(acc, bo0, bo1, ACT, w, c, g);

    BARX();   // ACT (new layer input / h2) visible
}

// ---------------- main fused kernel: 1 batch item / block, 256 threads ----------------
__global__ __launch_bounds__(256, 2) void drgn_pipe(
    const float* __restrict__ x, const int* __restrict__ maskg,
    const float* __restrict__ h0, const u16* __restrict__ W16,
    float* __restrict__ out_qs, float* __restrict__ out_h3)
{
    __shared__ __align__(16) u16 SMEM[24576];   // 49152 B: 3 x [64][128] bf16
    u16* ACT = SMEM;
    u16* QXp = SMEM + 8192;
    u16* KPp = SMEM + 16384;

    const int tid = threadIdx.x;
    const int w = tid >> 6, lane = tid & 63;
    const int c = lane & 15, g = lane >> 4;
    const int key = c & 7;
    const size_t rowbase = (size_t)blockIdx.x * 64;
    const u16* Wu = W16;
    const float* wsb = (const float*)(W16 + WS_BIAS_OFF);
    const int col00 = w*32 + g*4;
    const int col01 = col00 + 16;

    // ---- prologue ----
    u64* MrowT = (u64*)KPp;
    #pragma unroll 4
    for (int rr = 0; rr < 16; rr++){
        int row = w*16 + rr;
        int mv = __builtin_nontemporal_load(maskg + (rowbase + row)*64 + lane);
        u64 bits = __ballot(mv != 0);
        if (lane == 0) MrowT[row] = bits;
    }
    for (int i = tid; i < 512; i += 256){
        int row = i >> 3, p = i & 7;
        int lc = (p ^ (row & 7)) & 7;
        const float* sp = x + (rowbase + row)*64 + lc*8;
        f4v f0 = __builtin_nontemporal_load((const f4v*)sp);
        f4v f1 = __builtin_nontemporal_load((const f4v*)(sp + 4));
        uint4 o; o.x = pk2(f0.x,f0.y); o.y = pk2(f0.z,f0.w);
        o.z = pk2(f1.x,f1.y); o.w = pk2(f1.z,f1.w);
        *(uint4*)(QXp + row*128 + p*8) = o;
    }
    WB b_enc = load_unit<0>(Wu, w, lane);
    WB n0 = load_unit<1>(Wu, w, lane);
    WB n1 = load_unit<2>(Wu, w, lane);
    WB n2 = load_unit<3>(Wu, w, lane);
    __syncthreads();
    u64 mbits[4];
    #pragma unroll
    for (int qt = 0; qt < 4; qt++) mbits[qt] = MrowT[qt*16 + c];

    // ---- encoder ----
    {
        XF xf;
        f32x4 acc[2][4];
        float4 b0 = *(const float4*)(wsb + col00);
        float4 b1 = *(const float4*)(wsb + col01);
        loadX(xf, QXp, 0, c, g);
        wgemmW<true>(b_enc, xf, acc);
        epiW<false>(acc, b0, b1, ACT, w, c, g);
    }
    BARX();

    // ---- two MHA layers (prefetch threaded) ----
    mha_layer<0>(Wu, ACT, QXp, KPp, wsb, h0, rowbase, tid, w, lane, c, g, mbits,
                 n0, n1, n2, n0, n1, n2);
    mha_layer<1>(Wu, ACT, QXp, KPp, wsb, h0, rowbase, tid, w, lane, c, g, mbits,
                 n0, n1, n2, n0, n1, n2);   // returns g17,g18,g19

    // ---- GRU: ACT = h2, KPp = h0(bf16) ----
    XF xf;
    float rrA[2][4][4], zzA[2][4][4];
    WB g29, g30;
    {
        f32x4 aIr[2][4], aIz[2][4], aHr[2][4], aHz[2][4];
        loadX(xf, ACT, 0, c, g);
        wgemmW<true>(n0, xf, aIr);                       // r_ih0
        WB g20 = load_unit<20>(Wu, w, lane);
        wgemmW<true>(n1, xf, aIz);                       // z_ih0
        WB g21 = load_unit<21>(Wu, w, lane);
        loadX(xf, ACT, 1, c, g);
        wgemmW<false>(n2, xf, aIr);                      // r_ih1
        WB g22 = load_unit<22>(Wu, w, lane);
        wgemmW<false>(g20, xf, aIz);                     // z_ih1
        WB g23 = load_unit<23>(Wu, w, lane);
        loadX(xf, KPp, 0, c, g);
        wgemmW<true>(g21, xf, aHr);                      // r_hh0
        WB g24 = load_unit<24>(Wu, w, lane);
        wgemmW<true>(g22, xf, aHz);                      // z_hh0
        WB g25 = load_unit<25>(Wu, w, lane);
        loadX(xf, KPp, 1, c, g);
        wgemmW<false>(g23, xf, aHr);                     // r_hh1
        WB g26 = load_unit<26>(Wu, w, lane);
        wgemmW<false>(g24, xf, aHz);                     // z_hh1
        WB g27 = load_unit<27>(Wu, w, lane);

        float4 bir0 = *(const float4*)(wsb + 1152 + col00);
        float4 bir1 = *(const float4*)(wsb + 1152 + col01);
        float4 bhr0 = *(const float4*)(wsb + 1536 + col00);
        float4 bhr1 = *(const float4*)(wsb + 1536 + col01);
        float4 biz0 = *(const float4*)(wsb + 1152 + 128 + col00);
        float4 biz1 = *(const float4*)(wsb + 1152 + 128 + col01);
        float4 bhz0 = *(const float4*)(wsb + 1536 + 128 + col00);
        float4 bhz1 = *(const float4*)(wsb + 1536 + 128 + col01);
        #pragma unroll
        for (int i = 0; i < 2; i++){
            float4 bir = i ? bir1 : bir0; float4 bhr = i ? bhr1 : bhr0;
            float4 biz = i ? biz1 : biz0; float4 bhz = i ? bhz1 : bhz0;
            #pragma unroll
            for (int j = 0; j < 4; j++)
                #pragma unroll
                for (int r = 0; r < 4; r++){
                    rrA[i][j][r] = sigx(aIr[i][j][r] + (&bir.x)[r] + aHr[i][j][r] + (&bhr.x)[r]);
                    zzA[i][j][r] = sigx(aIz[i][j][r] + (&biz.x)[r] + aHz[i][j][r] + (&bhz.x)[r]);
                }
        }

        // n gate
        f32x4 aIn[2][4], aHn[2][4];
        loadX(xf, ACT, 0, c, g);
        wgemmW<true>(g25, xf, aIn);
        WB g28 = load_unit<28>(Wu, w, lane);
        loadX(xf, ACT, 1, c, g);
        wgemmW<false>(g26, xf, aIn);
        g29 = load_unit<29>(Wu, w, lane);
        loadX(xf, KPp, 0, c, g);
        wgemmW<true>(g27, xf, aHn);
        g30 = load_unit<30>(Wu, w, lane);
        loadX(xf, KPp, 1, c, g);
        wgemmW<false>(g28, xf, aHn);

        float4 bin0 = *(const float4*)(wsb + 1152 + 256 + col00);
        float4 bin1 = *(const float4*)(wsb + 1152 + 256 + col01);
        float4 bhn0 = *(const float4*)(wsb + 1536 + 256 + col00);
        float4 bhn1 = *(const float4*)(wsb + 1536 + 256 + col01);

        BARX();   // all waves' ACT/KPp reads done -> h3 may overwrite ACT

        #pragma unroll
        for (int i = 0; i < 2; i++){
            float4 bi = i ? bin1 : bin0; float4 bh = i ? bhn1 : bhn0;
            int col0 = w*32 + i*16 + g*4;
            int coff = swch(col0>>3, key)*8 + (col0&7);
            #pragma unroll
            for (int j = 0; j < 4; j++){
                int row = j*16 + c;
                uint2 hv = *(const uint2*)(KPp + row*128 + coff);
                float h0v[4] = { b2f((u16)(hv.x & 0xffffu)), b2f((u16)(hv.x >> 16)),
                                 b2f((u16)(hv.y & 0xffffu)), b2f((u16)(hv.y >> 16)) };
                f4v h3o;
                #pragma unroll
                for (int r = 0; r < 4; r++){
                    float xn = aIn[i][j][r] + (&bi.x)[r] + rrA[i][j][r]*(aHn[i][j][r] + (&bh.x)[r]);
                    float e2 = __builtin_amdgcn_exp2f(-2.f*L2E*fabsf(xn));
                    float th = (1.f - e2)*__builtin_amdgcn_rcpf(1.f + e2);
                    th = (xn >= 0.f) ? th : -th;
                    float zv = zzA[i][j][r];
                    h3o[r] = (1.f - zv)*th + zv*h0v[r];
                }
                uint2 o; o.x = pk2(h3o[0],h3o[1]); o.y = pk2(h3o[2],h3o[3]);
                *(uint2*)(ACT + row*128 + coff) = o;
                __builtin_nontemporal_store(h3o, (f4v*)(out_h3 + (rowbase + row)*128 + col0));
            }
        }
    }
    BARX();   // h3 visible

    // ---- final linear ----
    {
        f32x4 qa[2][4];
        float4 lb0 = (col00 < 20) ? *(const float4*)(wsb + 1920 + col00) : (float4){0.f,0.f,0.f,0.f};
        float4 lb1 = (col01 < 20) ? *(const float4*)(wsb + 1920 + col01) : (float4){0.f,0.f,0.f,0.f};
        loadX(xf, ACT, 0, c, g);
        wgemmW<true>(g29, xf, qa);
        loadX(xf, ACT, 1, c, g);
        wgemmW<false>(g30, xf, qa);

        #pragma unroll
        for (int i = 0; i < 2; i++){
            int col0 = w*32 + i*16 + g*4;
            if (col0 < 20){
                float4 lb = i ? lb1 : lb0;
                #pragma unroll
                for (int j = 0; j < 4; j++){
                    int row = j*16 + c;
                    f4v o;
                    o.x = qa[i][j][0]+lb.x; o.y = qa[i][j][1]+lb.y;
                    o.z = qa[i][j][2]+lb.z; o.w = qa[i][j][3]+lb.w;
                    __builtin_nontemporal_store(o, (f4v*)(out_qs + (rowbase + row)*20 + col0));
                }
            }
        }
    }
}

extern "C" void kernel_launch(void* const* d_in, const int* in_sizes, int n_in,
                              void* d_out, int out_size, void* d_ws, size_t ws_size,
                              hipStream_t stream) {
    const float* x     = (const float*)d_in[0];
    const int*   mask  = (const int*)  d_in[1];
    const float* h0    = (const float*)d_in[2];
    const float* enc_w = (const float*)d_in[3];
    const float* enc_b = (const float*)d_in[4];
    const float* q1_w  = (const float*)d_in[5];  const float* q1_b = (const float*)d_in[6];
    const float* k1_w  = (const float*)d_in[7];  const float* k1_b = (const float*)d_in[8];
    const float* v1_w  = (const float*)d_in[9];  const float* v1_b = (const float*)d_in[10];
    const float* o1_w  = (const float*)d_in[11]; const float* o1_b = (const float*)d_in[12];
    const float* q2_w  = (const float*)d_in[13]; const float* q2_b = (const float*)d_in[14];
    const float* k2_w  = (const float*)d_in[15]; const float* k2_b = (const float*)d_in[16];
    const float* v2_w  = (const float*)d_in[17]; const float* v2_b = (const float*)d_in[18];
    const float* o2_w  = (const float*)d_in[19]; const float* o2_b = (const float*)d_in[20];
    const float* gwih  = (const float*)d_in[21]; const float* gwhh = (const float*)d_in[22];
    const float* gbih  = (const float*)d_in[23]; const float* gbhh = (const float*)d_in[24];
    const float* lin_w = (const float*)d_in[25]; const float* lin_b = (const float*)d_in[26];

    const int bs = in_sizes[0] / (64 * 64);           // 4096
    float* out_qs = (float*)d_out;
    float* out_h3 = out_qs + (size_t)bs * 64 * 20;
    u16* W16 = (u16*)d_ws;

    const int total = NUNITS*8192 + NBIAS;
    hipLaunchKernelGGL(convert_weights, dim3((total + 255) / 256), dim3(256), 0, stream,
                       enc_w, q1_w, k1_w, v1_w, o1_w, q2_w, k2_w, v2_w, o2_w,
                       gwih, gwhh, lin_w,
                       enc_b, q1_b, k1_b, v1_b, o1_b, q2_b, k2_b, v2_b, o2_b,
                       gbih, gbhh, lin_b, W16);
    hipLaunchKernelGGL(drgn_pipe, dim3(bs), dim3(256), 0, stream,
                       x, mask, h0, W16, out_qs, out_h3);
}